// Round 6
// baseline (790.719 us; speedup 1.0000x reference)
//
#include <hip/hip_runtime.h>
#include <hip/hip_bf16.h>

typedef __bf16 bf16_t;
typedef __bf16 bf16x8 __attribute__((ext_vector_type(8)));
typedef float  f32x4  __attribute__((ext_vector_type(4)));
typedef float  f32x8  __attribute__((ext_vector_type(8)));

static __device__ __forceinline__ void gload_lds16(const void* g, void* l) {
  __builtin_amdgcn_global_load_lds((const __attribute__((address_space(1))) void*)g,
                                   (__attribute__((address_space(3))) void*)l, 16, 0, 0);
}

// LDS chunk swizzle for [rows][32] bf16 tiles (rows of 64B = 16 banks):
// chunk' = chunk ^ ((row>>1)&3)  ->  bank-set (row&1, chunk) distinct over
// 8 consecutive rows -> 2-way (free) instead of 8-way on ds_read_b128.

// ------------------------------------------------------------------
// GEMM  C = A * B^T (+bias, optional relu), A: MxK bf16, B: NxK bf16
// 128x128 tile, BK=32, 4 waves (2x2), 4x4 16x16x32 frags per wave.
// For grids >= 2 blocks/CU (QKV N=1536, FFN1 N=2048).
// ------------------------------------------------------------------
template <bool RELU, bool OUTBF>
__global__ __launch_bounds__(256)
void gemm_bt(const bf16_t* __restrict__ A, const bf16_t* __restrict__ B,
             const float* __restrict__ bias, void* __restrict__ Cv,
             int M, int N, int K, const int* __restrict__ flag)
{
  if (*flag) return;                       // step provably dead (all positions halted)
  __shared__ bf16_t As[128 * 32];
  __shared__ bf16_t Bs[128 * 32];
  const int tid = threadIdx.x;
  const int lane = tid & 63, wave = tid >> 6;
  const int wr = (wave >> 1) * 64, wc = (wave & 1) * 64;
  const int lr = lane & 15, lg = lane >> 4;
  const int m0 = blockIdx.x * 128, n0 = blockIdx.y * 128;

  const bf16_t* Ab = A + (size_t)m0 * K;
  const bf16_t* Bb = B + (size_t)n0 * K;

  f32x4 acc[4][4] = {};

  const int r0 = tid >> 2;                           // rows 0..63 (and +64)
  const int c0 = (((tid & 3) ^ ((r0 >> 1) & 3)) * 8); // inverse-swizzled source chunk
  const int lsw = (lg ^ ((lr >> 1) & 3)) * 8;         // swizzled read chunk

  for (int kk = 0; kk < K; kk += 32) {
    gload_lds16(Ab + (size_t)r0 * K + kk + c0, As + tid * 8);
    gload_lds16(Bb + (size_t)r0 * K + kk + c0, Bs + tid * 8);
    gload_lds16(Ab + (size_t)(r0 + 64) * K + kk + c0, As + (tid + 256) * 8);
    gload_lds16(Bb + (size_t)(r0 + 64) * K + kk + c0, Bs + (tid + 256) * 8);
    __syncthreads();
    bf16x8 af[4], bfr[4];
#pragma unroll
    for (int i = 0; i < 4; i++) af[i]  = *(const bf16x8*)(As + (wr + i * 16 + lr) * 32 + lsw);
#pragma unroll
    for (int j = 0; j < 4; j++) bfr[j] = *(const bf16x8*)(Bs + (wc + j * 16 + lr) * 32 + lsw);
#pragma unroll
    for (int i = 0; i < 4; i++)
#pragma unroll
      for (int j = 0; j < 4; j++)
        acc[i][j] = __builtin_amdgcn_mfma_f32_16x16x32_bf16(af[i], bfr[j], acc[i][j], 0, 0, 0);
    __syncthreads();
  }

  const int rg = (lane >> 4) * 4;
#pragma unroll
  for (int j = 0; j < 4; j++) {
    const int col = n0 + wc + j * 16 + lr;
    const float bv = bias ? bias[col] : 0.0f;
#pragma unroll
    for (int i = 0; i < 4; i++) {
#pragma unroll
      for (int r = 0; r < 4; r++) {
        const int row = m0 + wr + i * 16 + rg + r;
        float v = acc[i][j][r] + bv;
        if (RELU) v = fmaxf(v, 0.0f);
        if (OUTBF) ((bf16_t*)Cv)[(size_t)row * N + col] = (bf16_t)v;
        else       ((float*)Cv)[(size_t)row * N + col]  = v;
      }
    }
  }
}

// ------------------------------------------------------------------
// GEMM 128x128 tile, 512 threads / 8 waves (2 rows x 4 cols), each
// wave 64x32 (acc 4x2). For N=512 outputs (O-proj, FFN2): grid 256
// blocks = 1 block/CU but 2 waves/SIMD -> latency/barrier overlap.
// ------------------------------------------------------------------
template <bool RELU, bool OUTBF>
__global__ __launch_bounds__(512)
void gemm_bt512(const bf16_t* __restrict__ A, const bf16_t* __restrict__ B,
                const float* __restrict__ bias, void* __restrict__ Cv,
                int M, int N, int K, const int* __restrict__ flag)
{
  if (*flag) return;
  __shared__ bf16_t As[128 * 32];
  __shared__ bf16_t Bs[128 * 32];
  const int tid = threadIdx.x;
  const int lane = tid & 63, wave = tid >> 6;
  const int wr = (wave >> 2) * 64, wc = (wave & 3) * 32;
  const int lr = lane & 15, lg = lane >> 4;
  const int m0 = blockIdx.x * 128, n0 = blockIdx.y * 128;

  const bf16_t* Ab = A + (size_t)m0 * K;
  const bf16_t* Bb = B + (size_t)n0 * K;

  f32x4 acc[4][2] = {};

  const int r0 = tid >> 2;                            // rows 0..127
  const int c0 = (((tid & 3) ^ ((r0 >> 1) & 3)) * 8); // inverse-swizzled source chunk
  const int lsw = (lg ^ ((lr >> 1) & 3)) * 8;         // swizzled read chunk

  for (int kk = 0; kk < K; kk += 32) {
    gload_lds16(Ab + (size_t)r0 * K + kk + c0, As + tid * 8);
    gload_lds16(Bb + (size_t)r0 * K + kk + c0, Bs + tid * 8);
    __syncthreads();
    bf16x8 af[4], bfr[2];
#pragma unroll
    for (int i = 0; i < 4; i++) af[i]  = *(const bf16x8*)(As + (wr + i * 16 + lr) * 32 + lsw);
#pragma unroll
    for (int j = 0; j < 2; j++) bfr[j] = *(const bf16x8*)(Bs + (wc + j * 16 + lr) * 32 + lsw);
#pragma unroll
    for (int i = 0; i < 4; i++)
#pragma unroll
      for (int j = 0; j < 2; j++)
        acc[i][j] = __builtin_amdgcn_mfma_f32_16x16x32_bf16(af[i], bfr[j], acc[i][j], 0, 0, 0);
    __syncthreads();
  }

  const int rg = (lane >> 4) * 4;
#pragma unroll
  for (int j = 0; j < 2; j++) {
    const int col = n0 + wc + j * 16 + lr;
    const float bv = bias ? bias[col] : 0.0f;
#pragma unroll
    for (int i = 0; i < 4; i++) {
#pragma unroll
      for (int r = 0; r < 4; r++) {
        const int row = m0 + wr + i * 16 + rg + r;
        float v = acc[i][j][r] + bv;
        if (RELU) v = fmaxf(v, 0.0f);
        if (OUTBF) ((bf16_t*)Cv)[(size_t)row * N + col] = (bf16_t)v;
        else       ((float*)Cv)[(size_t)row * N + col]  = v;
      }
    }
  }
}

// ------------------------------------------------------------------
// V transpose: per (b,h), V (1024 keys x 64 d) -> VT (64 d x 1024 keys).
// ------------------------------------------------------------------
__global__ __launch_bounds__(256)
void k_vtrans(const bf16_t* __restrict__ qkv, bf16_t* __restrict__ vt,
              const int* __restrict__ flag)
{
  if (*flag) return;
  __shared__ bf16_t T[64][72];             // 64 keys x 64 d, pitch 72
  const int bh = blockIdx.x, kt = blockIdx.y;
  const int b = bh >> 3, h = bh & 7;
  const int t = threadIdx.x;
  const bf16_t* Vb = qkv + ((size_t)(b * 1024 + kt * 64)) * 1536 + 1024 + h * 64;
  {
    const int c = t & 7, r = t >> 3;       // r in 0..31
    *(bf16x8*)&T[r][c * 8]      = *(const bf16x8*)(Vb + (size_t)r * 1536 + c * 8);
    *(bf16x8*)&T[r + 32][c * 8] = *(const bf16x8*)(Vb + (size_t)(r + 32) * 1536 + c * 8);
  }
  __syncthreads();
  bf16_t* O = vt + ((size_t)bh * 64) * 1024 + (size_t)kt * 64;
  {
    const int d = t >> 2, kc = t & 3;      // d 0..63
#pragma unroll
    for (int half = 0; half < 2; half++) {
      const int k0 = (kc + 4 * half) * 8;
      bf16x8 v;
#pragma unroll
      for (int u = 0; u < 8; u++) v[u] = T[k0 + u][d];
      *(bf16x8*)(O + (size_t)d * 1024 + k0) = v;
    }
  }
}

// ------------------------------------------------------------------
// Flash attention v4: QBLK=128 (8 waves, 512 threads); K and V^T
// tiles double-buffered in LDS with XOR swizzle; in-register online
// softmax with defer-max; setprio around MFMA clusters.
// ------------------------------------------------------------------
__global__ __launch_bounds__(512)
void k_attn(const bf16_t* __restrict__ qkv, const bf16_t* __restrict__ vt,
            bf16_t* __restrict__ out, const int* __restrict__ flag)
{
  if (*flag) return;
  const int bh = blockIdx.x;            // b*8+h
  const int qt = blockIdx.y;            // 0..7
  const int b = bh >> 3, h = bh & 7;
  const int tid = threadIdx.x, lane = tid & 63, wave = tid >> 6;
  const int lr = lane & 15, lg = lane >> 4;

  __shared__ bf16_t Ks[2][4096];        // [buf][key*64 + d^swz]
  __shared__ bf16_t Vs[2][4096];        // [buf][d*64 + key^swz]
  __shared__ bf16_t Pl[8][16][68];      // [wave][q][key]

  const size_t RS = 1536;
  const bf16_t* Qb = qkv + ((size_t)(b * 1024 + qt * 128)) * RS + h * 64;
  const bf16_t* Kb = qkv + ((size_t)(b * 1024)) * RS + 512 + h * 64;
  const bf16_t* Vt = vt + (size_t)bh * 64 * 1024;

  // Q fragment, pre-scaled by 1/sqrt(d) * log2(e) so S is in log2 units.
  const float SC = 0.125f * 1.4426950408889634f;
  bf16x8 qf[2];
#pragma unroll
  for (int ks = 0; ks < 2; ks++) {
    bf16x8 q = *(const bf16x8*)(Qb + (size_t)(wave * 16 + lr) * RS + lg * 8 + ks * 32);
#pragma unroll
    for (int u = 0; u < 8; u++) q[u] = (bf16_t)((float)q[u] * SC);
    qf[ks] = q;
  }

  f32x4 o[4] = {};
  float m[4], ls[4];
#pragma unroll
  for (int r = 0; r < 4; r++) { m[r] = -1e30f; ls[r] = 0.0f; }

  // staging: 512 threads x 1 chunk of 16B per matrix (8KB each for K, VT)
  auto stage = [&](int buf, int kv) {
    const int c = tid;
    const int r = c >> 3;                        // tile row 0..63
    const int ce = (c & 7) * 8;                  // element col
    const int cs = ce ^ ((r & 7) << 3);          // inverse-swizzled source col
    gload_lds16(Kb + (size_t)(kv * 64 + r) * RS + cs, &Ks[buf][c * 8]);
    gload_lds16(Vt + (size_t)r * 1024 + kv * 64 + cs, &Vs[buf][c * 8]);
  };

  stage(0, 0);
  __syncthreads();

  const int sw = (lr & 7) << 3;                  // read-side swizzle

  for (int kv = 0; kv < 16; kv++) {
    const int buf = kv & 1;
    if (kv < 15) stage(buf ^ 1, kv + 1);         // prefetch next tile

    // ---- S = Q K^T (log2 units) ----
    f32x4 sfr[4];
    __builtin_amdgcn_s_setprio(1);
#pragma unroll
    for (int j = 0; j < 4; j++) {
      f32x4 z = {};
#pragma unroll
      for (int ks = 0; ks < 2; ks++) {
        bf16x8 kf = *(const bf16x8*)(&Ks[buf][(j * 16 + lr) * 64 + ((lg * 8 + ks * 32) ^ sw)]);
        z = __builtin_amdgcn_mfma_f32_16x16x32_bf16(qf[ks], kf, z, 0, 0, 0);
      }
      sfr[j] = z;
    }
    __builtin_amdgcn_s_setprio(0);

    // ---- defer-max online softmax ----
    float px[4];
#pragma unroll
    for (int r = 0; r < 4; r++)
      px[r] = fmaxf(fmaxf(sfr[0][r], sfr[1][r]), fmaxf(sfr[2][r], sfr[3][r]));
    bool ok = (px[0] <= m[0] + 8.0f) && (px[1] <= m[1] + 8.0f) &&
              (px[2] <= m[2] + 8.0f) && (px[3] <= m[3] + 8.0f);
    if (!__all(ok)) {
#pragma unroll
      for (int r = 0; r < 4; r++) {
        float mx = px[r];
#pragma unroll
        for (int mk = 1; mk < 16; mk <<= 1) mx = fmaxf(mx, __shfl_xor(mx, mk, 64));
        mx = fmaxf(mx, m[r]);
        const float al = __builtin_amdgcn_exp2f(m[r] - mx);
        m[r] = mx;
        ls[r] *= al;
#pragma unroll
        for (int j = 0; j < 4; j++) o[j][r] *= al;
      }
    }

    // ---- P = exp2(S - m); lane-partial row sums ----
#pragma unroll
    for (int j = 0; j < 4; j++)
#pragma unroll
      for (int r = 0; r < 4; r++) {
        const float p = __builtin_amdgcn_exp2f(sfr[j][r] - m[r]);
        ls[r] += p;
        Pl[wave][lg * 4 + r][j * 16 + lr] = (bf16_t)p;
      }

    // ---- O += P * V ----
    __builtin_amdgcn_s_setprio(1);
#pragma unroll
    for (int ks = 0; ks < 2; ks++) {
      bf16x8 pa = *(const bf16x8*)(&Pl[wave][lr][lg * 8 + ks * 32]);
#pragma unroll
      for (int j = 0; j < 4; j++) {
        bf16x8 vb = *(const bf16x8*)(&Vs[buf][(j * 16 + lr) * 64 + ((lg * 8 + ks * 32) ^ sw)]);
        o[j] = __builtin_amdgcn_mfma_f32_16x16x32_bf16(pa, vb, o[j], 0, 0, 0);
      }
    }
    __builtin_amdgcn_s_setprio(0);

    __syncthreads();   // staged tile ready; all waves done reading buf
  }

#pragma unroll
  for (int r = 0; r < 4; r++)
#pragma unroll
    for (int mk = 1; mk < 16; mk <<= 1) ls[r] += __shfl_xor(ls[r], mk, 64);

  const size_t orow = (size_t)(b * 1024 + qt * 128 + wave * 16 + lg * 4);
#pragma unroll
  for (int j = 0; j < 4; j++)
#pragma unroll
    for (int r = 0; r < 4; r++)
      out[(orow + r) * 512 + h * 64 + j * 16 + lr] = (bf16_t)(o[j][r] / ls[r]);
}

// ------------------------------------------------------------------
// s += pos + ts[step]; p = sigmoid(s . p_w + p_b); ACT halting update.
// Also emits bf16 copy of s for the QKV GEMM.
// ------------------------------------------------------------------
__global__ __launch_bounds__(256)
void k_poshalt(float* __restrict__ s, bf16_t* __restrict__ xbf,
               const float* __restrict__ pos, const float* __restrict__ ts, int step,
               const float* __restrict__ pw, const float* __restrict__ pb,
               float* __restrict__ hp, float* __restrict__ rem, float* __restrict__ uw,
               const int* __restrict__ flag)
{
  if (*flag) return;
  const int row = blockIdx.x;
  const int l = row & 1023;
  const int t = threadIdx.x;
  const size_t base = (size_t)row * 512;
  float v0 = s[base + t]       + pos[l * 512 + t]       + ts[step * 512 + t];
  float v1 = s[base + 256 + t] + pos[l * 512 + 256 + t] + ts[step * 512 + 256 + t];
  s[base + t] = v0; s[base + 256 + t] = v1;
  xbf[base + t] = (bf16_t)v0; xbf[base + 256 + t] = (bf16_t)v1;

  float d = v0 * pw[t] + v1 * pw[256 + t];
#pragma unroll
  for (int mk = 1; mk < 64; mk <<= 1) d += __shfl_xor(d, mk, 64);
  __shared__ float part[4];
  if ((t & 63) == 0) part[t >> 6] = d;
  __syncthreads();
  if (t == 0) {
    const float z = part[0] + part[1] + part[2] + part[3] + pb[0];
    const float p = 1.0f / (1.0f + expf(-z));
    float h  = (step == 0) ? 0.0f : hp[row];
    float rm = (step == 0) ? 0.0f : rem[row];
    const float still0 = (h < 1.0f) ? 1.0f : 0.0f;
    const float cond = h + p * still0;
    const float nh = (cond > 0.9f) ? still0 : 0.0f;
    const float st = (cond <= 0.9f) ? still0 : 0.0f;
    h += p * st;
    rm += nh * (1.0f - h);
    h += nh * rm;
    hp[row] = h; rem[row] = rm;
    uw[row] = p * st + nh * rm;
  }
}

// ------------------------------------------------------------------
// y = LayerNorm(xa + xb) * g + be.
// UPDATE=false: write y (fp32) + y (bf16)      [post-attn LN]
// UPDATE=true : write y to s; prev = y*uw + prev*(1-uw), skipping
//               the prev R/M/W when uw==0 (halted row)  [post-FFN LN]
// ------------------------------------------------------------------
template <bool UPDATE>
__global__ __launch_bounds__(256)
void k_addln(const float* __restrict__ xa, const float* __restrict__ xb,
             const float* __restrict__ g, const float* __restrict__ be,
             float* __restrict__ yout, bf16_t* __restrict__ ybf,
             const float* __restrict__ uw, float* __restrict__ prev, int step,
             const int* __restrict__ flag)
{
  if (*flag) return;
  const int row = blockIdx.x, t = threadIdx.x;
  const size_t base = (size_t)row * 512;
  const float v0 = xa[base + t] + xb[base + t];
  const float v1 = xa[base + 256 + t] + xb[base + 256 + t];
  float s1 = v0 + v1, s2 = v0 * v0 + v1 * v1;
#pragma unroll
  for (int mk = 1; mk < 64; mk <<= 1) { s1 += __shfl_xor(s1, mk, 64); s2 += __shfl_xor(s2, mk, 64); }
  __shared__ float p1[4], p2[4];
  if ((t & 63) == 0) { p1[t >> 6] = s1; p2[t >> 6] = s2; }
  __syncthreads();
  s1 = p1[0] + p1[1] + p1[2] + p1[3];
  s2 = p2[0] + p2[1] + p2[2] + p2[3];
  const float mean = s1 * (1.0f / 512.0f);
  const float var  = s2 * (1.0f / 512.0f) - mean * mean;
  const float ri = rsqrtf(var + 1e-5f);
  const float y0 = (v0 - mean) * ri * g[t]       + be[t];
  const float y1 = (v1 - mean) * ri * g[256 + t] + be[256 + t];
  if (UPDATE) {
    yout[base + t] = y0; yout[base + 256 + t] = y1;       // new state s
    const float w = uw[row];
    if (step == 0) {
      prev[base + t] = y0 * w; prev[base + 256 + t] = y1 * w;
    } else if (w != 0.0f) {
      const float pv0 = prev[base + t];
      const float pv1 = prev[base + 256 + t];
      prev[base + t]       = y0 * w + pv0 * (1.0f - w);
      prev[base + 256 + t] = y1 * w + pv1 * (1.0f - w);
    }
  } else {
    yout[base + t] = y0; yout[base + 256 + t] = y1;       // x1 fp32
    ybf[base + t] = (bf16_t)y0; ybf[base + 256 + t] = (bf16_t)y1;
  }
}

// ------------------------------------------------------------------
// All-halted detector: flag = 1 once min(hp) >= 1.0 (then uw == 0
// forever -> remaining steps provably dead w.r.t. prev).
// ------------------------------------------------------------------
__global__ __launch_bounds__(256)
void k_flag(const float* __restrict__ hp, int* __restrict__ flag)
{
  if (*flag) return;
  const int t = threadIdx.x;
  float mn = 1e30f;
#pragma unroll
  for (int i = 0; i < 4; i++) {
    f32x8 v = *(const f32x8*)(hp + (t + i * 256) * 8);
#pragma unroll
    for (int u = 0; u < 8; u++) mn = fminf(mn, v[u]);
  }
#pragma unroll
  for (int mk = 1; mk < 64; mk <<= 1) mn = fminf(mn, __shfl_xor(mn, mk, 64));
  __shared__ float part[4];
  if ((t & 63) == 0) part[t >> 6] = mn;
  __syncthreads();
  if (t == 0) {
    mn = fminf(fminf(part[0], part[1]), fminf(part[2], part[3]));
    if (mn >= 1.0f) *flag = 1;
  }
}

__global__ void k_zeroflag(int* __restrict__ flag) { *flag = 0; }

// ------------------------------------------------------------------
// Positional / timing tables (matches numpy f32 formula).
// ------------------------------------------------------------------
__global__ void k_pos_ts(float* __restrict__ pos, float* __restrict__ ts,
                         const int* __restrict__ outer)
{
  const int idx = blockIdx.x * 256 + threadIdx.x;   // 0 .. 1024*512-1
  const int l = idx >> 9, i = idx & 511;
  const float dt = expf((float)(i & ~1) * (-9.210340371976184f / 512.0f));
  const float a = (float)l * dt;
  pos[idx] = (i & 1) ? cosf(a) : sinf(a);
  if (l < 6) {
    const int gidx = 6 * outer[0] + l;
    const float a2 = (float)gidx * dt;
    ts[l * 512 + i] = (i & 1) ? cosf(a2) : sinf(a2);
  }
}

__global__ void k_f2b(const float* __restrict__ in, bf16_t* __restrict__ out, int n)
{
  const int i = blockIdx.x * 256 + threadIdx.x;
  if (i < n) out[i] = (bf16_t)in[i];
}

__global__ void k_copy(const float* __restrict__ in, float* __restrict__ out, int n)
{
  const int i = blockIdx.x * 256 + threadIdx.x;
  if (i < n) out[i] = in[i];
}

// ------------------------------------------------------------------
extern "C" void kernel_launch(void* const* d_in, const int* in_sizes, int n_in,
                              void* d_out, int out_size, void* d_ws, size_t ws_size,
                              hipStream_t stream)
{
  const float* state = (const float*)d_in[0];
  const int*   outer = (const int*)d_in[1];
  const float* p_w   = (const float*)d_in[2];
  const float* p_b   = (const float*)d_in[3];
  const float* wq = (const float*)d_in[4];
  const float* bq = (const float*)d_in[5];
  const float* wk = (const float*)d_in[6];
  const float* bk = (const float*)d_in[7];
  const float* wv = (const float*)d_in[8];
  const float* bv = (const float*)d_in[9];
  const float* wo = (const float*)d_in[10];
  const float* bo = (const float*)d_in[11];
  const float* w1 = (const float*)d_in[12];
  const float* b1 = (const float*)d_in[13];
  const float* w2 = (const float*)d_in[14];
  const float* b2 = (const float*)d_in[15];
  const float* ln1g = (const float*)d_in[16];
  const float* ln1b = (const float*)d_in[17];
  const float* ln2g = (const float*)d_in[18];
  const float* ln2b = (const float*)d_in[19];
  float* prev = (float*)d_out;

  char* cur = (char*)d_ws;
  auto take = [&](size_t n) { char* p = cur; cur += (n + 255) & ~(size_t)255; return p; };
  float*  pos   = (float*) take((size_t)1024 * 512 * 4);
  float*  ts    = (float*) take(6 * 512 * 4);
  bf16_t* wqkvB = (bf16_t*)take((size_t)1536 * 512 * 2);
  bf16_t* woB   = (bf16_t*)take((size_t)512 * 512 * 2);
  bf16_t* w1B   = (bf16_t*)take((size_t)2048 * 512 * 2);
  bf16_t* w2B   = (bf16_t*)take((size_t)512 * 2048 * 2);
  float*  bqkv  = (float*) take(1536 * 4);
  float*  s     = (float*) take((size_t)8192 * 512 * 4);
  float*  x1    = (float*) take((size_t)8192 * 512 * 4);
  bf16_t* x1B   = (bf16_t*)take((size_t)8192 * 512 * 2);
  float*  tmp   = (float*) take((size_t)8192 * 512 * 4);   // also hosts vt (bf16, 8.4MB) while dead
  bf16_t* attnO = (bf16_t*)take((size_t)8192 * 512 * 2);
  float*  hp    = (float*) take(8192 * 4);
  float*  rem   = (float*) take(8192 * 4);
  float*  uw    = (float*) take(8192 * 4);
  int*    flag  = (int*)   take(4);
  char*   region = take((size_t)8192 * 2048 * 2);           // 33.5 MB, time-shared
  bf16_t* xB  = (bf16_t*)region;                            // 8192x512  (dead after QKV gemm)
  bf16_t* qkv = (bf16_t*)(region + (size_t)8192 * 512 * 2); // 8192x1536 (dead after attn)
  bf16_t* hB  = (bf16_t*)region;                            // 8192x2048 (FFN intermediate)
  bf16_t* vt  = (bf16_t*)tmp;                               // 64x64x1024 (dead before O-proj writes tmp)

  // ---- precompute ----
  k_zeroflag<<<dim3(1), dim3(1), 0, stream>>>(flag);
  k_pos_ts<<<dim3(2048), dim3(256), 0, stream>>>(pos, ts, outer);
  k_f2b<<<dim3(1024), dim3(256), 0, stream>>>(wq, wqkvB,               512 * 512);
  k_f2b<<<dim3(1024), dim3(256), 0, stream>>>(wk, wqkvB + 512 * 512,   512 * 512);
  k_f2b<<<dim3(1024), dim3(256), 0, stream>>>(wv, wqkvB + 1024 * 512,  512 * 512);
  k_f2b<<<dim3(1024), dim3(256), 0, stream>>>(wo, woB,                 512 * 512);
  k_f2b<<<dim3(4096), dim3(256), 0, stream>>>(w1, w1B,                 2048 * 512);
  k_f2b<<<dim3(4096), dim3(256), 0, stream>>>(w2, w2B,                 512 * 2048);
  k_copy<<<dim3(2), dim3(256), 0, stream>>>(bq, bqkv,        512);
  k_copy<<<dim3(2), dim3(256), 0, stream>>>(bk, bqkv + 512,  512);
  k_copy<<<dim3(2), dim3(256), 0, stream>>>(bv, bqkv + 1024, 512);
  k_copy<<<dim3(16384), dim3(256), 0, stream>>>(state, s, 8192 * 512);

  // ---- 6 hops ----
  for (int step = 0; step < 6; step++) {
    k_poshalt<<<dim3(8192), dim3(256), 0, stream>>>(s, xB, pos, ts, step, p_w, p_b, hp, rem, uw, flag);
    gemm_bt<false, true ><<<dim3(64, 12), dim3(256), 0, stream>>>(xB, wqkvB, bqkv, (void*)qkv, 8192, 1536, 512, flag);
    k_vtrans<<<dim3(64, 16), dim3(256), 0, stream>>>(qkv, vt, flag);
    k_attn<<<dim3(64, 8), dim3(512), 0, stream>>>(qkv, vt, attnO, flag);
    gemm_bt512<false, false><<<dim3(64, 4), dim3(512), 0, stream>>>(attnO, woB, bo, (void*)tmp, 8192, 512, 512, flag);
    k_addln<false><<<dim3(8192), dim3(256), 0, stream>>>(s, tmp, ln1g, ln1b, x1, x1B, nullptr, nullptr, step, flag);
    gemm_bt<true,  true ><<<dim3(64, 16), dim3(256), 0, stream>>>(x1B, w1B, b1, (void*)hB, 8192, 2048, 512, flag);
    gemm_bt512<false, false><<<dim3(64, 4), dim3(512), 0, stream>>>(hB, w2B, b2, (void*)tmp, 8192, 512, 2048, flag);
    k_addln<true ><<<dim3(8192), dim3(256), 0, stream>>>(x1, tmp, ln2g, ln2b, s, nullptr, uw, prev, step, flag);
    if (step < 5)
      k_flag<<<dim3(1), dim3(256), 0, stream>>>(hp, flag);
  }
}

// Round 7
// 762.618 us; speedup vs baseline: 1.0368x; 1.0368x over previous
//
#include <hip/hip_runtime.h>
#include <hip/hip_bf16.h>

typedef __bf16 bf16_t;
typedef __bf16 bf16x8 __attribute__((ext_vector_type(8)));
typedef float  f32x4  __attribute__((ext_vector_type(4)));
typedef float  f32x8  __attribute__((ext_vector_type(8)));

static __device__ __forceinline__ void gload_lds16(const void* g, void* l) {
  __builtin_amdgcn_global_load_lds((const __attribute__((address_space(1))) void*)g,
                                   (__attribute__((address_space(3))) void*)l, 16, 0, 0);
}

// LDS chunk swizzle for [rows][32] bf16 tiles: chunk' = chunk ^ ((row>>1)&3).

// ------------------------------------------------------------------
// GEMM  C = A*B^T (+bias, relu opt). 128x128 tile, BK=32, 4 waves,
// 2-phase double-buffered: stage(next) BEFORE compute(cur), 1 barrier
// per K-step. For QKV (N=1536) / FFN1 (N=2048) grids (>=3 blocks/CU).
// ------------------------------------------------------------------
template <bool RELU, bool OUTBF>
__global__ __launch_bounds__(256)
void gemm_bt(const bf16_t* __restrict__ A, const bf16_t* __restrict__ B,
             const float* __restrict__ bias, void* __restrict__ Cv,
             int M, int N, int K, const int* __restrict__ flag)
{
  if (*flag) return;
  __shared__ bf16_t As[2][128 * 32];
  __shared__ bf16_t Bs[2][128 * 32];
  const int tid = threadIdx.x;
  const int lane = tid & 63, wave = tid >> 6;
  const int wr = (wave >> 1) * 64, wc = (wave & 1) * 64;
  const int lr = lane & 15, lg = lane >> 4;
  const int m0 = blockIdx.x * 128, n0 = blockIdx.y * 128;

  const bf16_t* Ab = A + (size_t)m0 * K;
  const bf16_t* Bb = B + (size_t)n0 * K;

  f32x4 acc[4][4] = {};

  const int r0 = tid >> 2;                            // rows 0..63 (and +64)
  const int c0 = (((tid & 3) ^ ((r0 >> 1) & 3)) * 8); // inverse-swizzled source chunk
  const int lsw = (lg ^ ((lr >> 1) & 3)) * 8;         // swizzled read chunk

  auto stage = [&](int buf, int kk) {
    gload_lds16(Ab + (size_t)r0 * K + kk + c0,        &As[buf][tid * 8]);
    gload_lds16(Bb + (size_t)r0 * K + kk + c0,        &Bs[buf][tid * 8]);
    gload_lds16(Ab + (size_t)(r0 + 64) * K + kk + c0, &As[buf][(tid + 256) * 8]);
    gload_lds16(Bb + (size_t)(r0 + 64) * K + kk + c0, &Bs[buf][(tid + 256) * 8]);
  };

  stage(0, 0);
  __syncthreads();

  const int nk = K >> 5;
  for (int t = 0; t < nk; ++t) {
    const int buf = t & 1;
    if (t + 1 < nk) stage(buf ^ 1, (t + 1) * 32);     // prefetch next K-tile
    bf16x8 af[4], bfr[4];
#pragma unroll
    for (int i = 0; i < 4; i++) af[i]  = *(const bf16x8*)(&As[buf][(wr + i * 16 + lr) * 32 + lsw]);
#pragma unroll
    for (int j = 0; j < 4; j++) bfr[j] = *(const bf16x8*)(&Bs[buf][(wc + j * 16 + lr) * 32 + lsw]);
#pragma unroll
    for (int i = 0; i < 4; i++)
#pragma unroll
      for (int j = 0; j < 4; j++)
        acc[i][j] = __builtin_amdgcn_mfma_f32_16x16x32_bf16(af[i], bfr[j], acc[i][j], 0, 0, 0);
    __syncthreads();                                   // next tile staged; cur reads done
  }

  const int rg = (lane >> 4) * 4;
#pragma unroll
  for (int j = 0; j < 4; j++) {
    const int col = n0 + wc + j * 16 + lr;
    const float bv = bias ? bias[col] : 0.0f;
#pragma unroll
    for (int i = 0; i < 4; i++) {
#pragma unroll
      for (int r = 0; r < 4; r++) {
        const int row = m0 + wr + i * 16 + rg + r;
        float v = acc[i][j][r] + bv;
        if (RELU) v = fmaxf(v, 0.0f);
        if (OUTBF) ((bf16_t*)Cv)[(size_t)row * N + col] = (bf16_t)v;
        else       ((float*)Cv)[(size_t)row * N + col]  = v;
      }
    }
  }
}

// ------------------------------------------------------------------
// GEMM 128x128, 512 threads / 8 waves (2x4), wave = 64x32 (acc 4x2),
// same 2-phase dbuf schedule. For N=512 outputs (O-proj, FFN2).
// ------------------------------------------------------------------
template <bool RELU, bool OUTBF>
__global__ __launch_bounds__(512)
void gemm_bt512(const bf16_t* __restrict__ A, const bf16_t* __restrict__ B,
                const float* __restrict__ bias, void* __restrict__ Cv,
                int M, int N, int K, const int* __restrict__ flag)
{
  if (*flag) return;
  __shared__ bf16_t As[2][128 * 32];
  __shared__ bf16_t Bs[2][128 * 32];
  const int tid = threadIdx.x;
  const int lane = tid & 63, wave = tid >> 6;
  const int wr = (wave >> 2) * 64, wc = (wave & 3) * 32;
  const int lr = lane & 15, lg = lane >> 4;
  const int m0 = blockIdx.x * 128, n0 = blockIdx.y * 128;

  const bf16_t* Ab = A + (size_t)m0 * K;
  const bf16_t* Bb = B + (size_t)n0 * K;

  f32x4 acc[4][2] = {};

  const int r0 = tid >> 2;                            // rows 0..127
  const int c0 = (((tid & 3) ^ ((r0 >> 1) & 3)) * 8);
  const int lsw = (lg ^ ((lr >> 1) & 3)) * 8;

  auto stage = [&](int buf, int kk) {
    gload_lds16(Ab + (size_t)r0 * K + kk + c0, &As[buf][tid * 8]);
    gload_lds16(Bb + (size_t)r0 * K + kk + c0, &Bs[buf][tid * 8]);
  };

  stage(0, 0);
  __syncthreads();

  const int nk = K >> 5;
  for (int t = 0; t < nk; ++t) {
    const int buf = t & 1;
    if (t + 1 < nk) stage(buf ^ 1, (t + 1) * 32);
    bf16x8 af[4], bfr[2];
#pragma unroll
    for (int i = 0; i < 4; i++) af[i]  = *(const bf16x8*)(&As[buf][(wr + i * 16 + lr) * 32 + lsw]);
#pragma unroll
    for (int j = 0; j < 2; j++) bfr[j] = *(const bf16x8*)(&Bs[buf][(wc + j * 16 + lr) * 32 + lsw]);
#pragma unroll
    for (int i = 0; i < 4; i++)
#pragma unroll
      for (int j = 0; j < 2; j++)
        acc[i][j] = __builtin_amdgcn_mfma_f32_16x16x32_bf16(af[i], bfr[j], acc[i][j], 0, 0, 0);
    __syncthreads();
  }

  const int rg = (lane >> 4) * 4;
#pragma unroll
  for (int j = 0; j < 2; j++) {
    const int col = n0 + wc + j * 16 + lr;
    const float bv = bias ? bias[col] : 0.0f;
#pragma unroll
    for (int i = 0; i < 4; i++) {
#pragma unroll
      for (int r = 0; r < 4; r++) {
        const int row = m0 + wr + i * 16 + rg + r;
        float v = acc[i][j][r] + bv;
        if (RELU) v = fmaxf(v, 0.0f);
        if (OUTBF) ((bf16_t*)Cv)[(size_t)row * N + col] = (bf16_t)v;
        else       ((float*)Cv)[(size_t)row * N + col]  = v;
      }
    }
  }
}

// ------------------------------------------------------------------
// V transpose: per (b,h), V (1024 keys x 64 d) -> VT (64 d x 1024 keys).
// ------------------------------------------------------------------
__global__ __launch_bounds__(256)
void k_vtrans(const bf16_t* __restrict__ qkv, bf16_t* __restrict__ vt,
              const int* __restrict__ flag)
{
  if (*flag) return;
  __shared__ bf16_t T[64][72];
  const int bh = blockIdx.x, kt = blockIdx.y;
  const int b = bh >> 3, h = bh & 7;
  const int t = threadIdx.x;
  const bf16_t* Vb = qkv + ((size_t)(b * 1024 + kt * 64)) * 1536 + 1024 + h * 64;
  {
    const int c = t & 7, r = t >> 3;
    *(bf16x8*)&T[r][c * 8]      = *(const bf16x8*)(Vb + (size_t)r * 1536 + c * 8);
    *(bf16x8*)&T[r + 32][c * 8] = *(const bf16x8*)(Vb + (size_t)(r + 32) * 1536 + c * 8);
  }
  __syncthreads();
  bf16_t* O = vt + ((size_t)bh * 64) * 1024 + (size_t)kt * 64;
  {
    const int d = t >> 2, kc = t & 3;
#pragma unroll
    for (int half = 0; half < 2; half++) {
      const int k0 = (kc + 4 * half) * 8;
      bf16x8 v;
#pragma unroll
      for (int u = 0; u < 8; u++) v[u] = T[k0 + u][d];
      *(bf16x8*)(O + (size_t)d * 1024 + k0) = v;
    }
  }
}

// ------------------------------------------------------------------
// Flash attention: QBLK=128 (8 waves); K/V^T double-buffered in LDS
// (XOR swizzle, stage-before-compute); in-register online softmax
// with defer-max; setprio around MFMA clusters.
// ------------------------------------------------------------------
__global__ __launch_bounds__(512)
void k_attn(const bf16_t* __restrict__ qkv, const bf16_t* __restrict__ vt,
            bf16_t* __restrict__ out, const int* __restrict__ flag)
{
  if (*flag) return;
  const int bh = blockIdx.x;
  const int qt = blockIdx.y;
  const int b = bh >> 3, h = bh & 7;
  const int tid = threadIdx.x, lane = tid & 63, wave = tid >> 6;
  const int lr = lane & 15, lg = lane >> 4;

  __shared__ bf16_t Ks[2][4096];
  __shared__ bf16_t Vs[2][4096];
  __shared__ bf16_t Pl[8][16][68];

  const size_t RS = 1536;
  const bf16_t* Qb = qkv + ((size_t)(b * 1024 + qt * 128)) * RS + h * 64;
  const bf16_t* Kb = qkv + ((size_t)(b * 1024)) * RS + 512 + h * 64;
  const bf16_t* Vt = vt + (size_t)bh * 64 * 1024;

  const float SC = 0.125f * 1.4426950408889634f;
  bf16x8 qf[2];
#pragma unroll
  for (int ks = 0; ks < 2; ks++) {
    bf16x8 q = *(const bf16x8*)(Qb + (size_t)(wave * 16 + lr) * RS + lg * 8 + ks * 32);
#pragma unroll
    for (int u = 0; u < 8; u++) q[u] = (bf16_t)((float)q[u] * SC);
    qf[ks] = q;
  }

  f32x4 o[4] = {};
  float m[4], ls[4];
#pragma unroll
  for (int r = 0; r < 4; r++) { m[r] = -1e30f; ls[r] = 0.0f; }

  auto stage = [&](int buf, int kv) {
    const int c = tid;
    const int r = c >> 3;
    const int ce = (c & 7) * 8;
    const int cs = ce ^ ((r & 7) << 3);
    gload_lds16(Kb + (size_t)(kv * 64 + r) * RS + cs, &Ks[buf][c * 8]);
    gload_lds16(Vt + (size_t)r * 1024 + kv * 64 + cs, &Vs[buf][c * 8]);
  };

  stage(0, 0);
  __syncthreads();

  const int sw = (lr & 7) << 3;

  for (int kv = 0; kv < 16; kv++) {
    const int buf = kv & 1;
    if (kv < 15) stage(buf ^ 1, kv + 1);

    f32x4 sfr[4];
    __builtin_amdgcn_s_setprio(1);
#pragma unroll
    for (int j = 0; j < 4; j++) {
      f32x4 z = {};
#pragma unroll
      for (int ks = 0; ks < 2; ks++) {
        bf16x8 kf = *(const bf16x8*)(&Ks[buf][(j * 16 + lr) * 64 + ((lg * 8 + ks * 32) ^ sw)]);
        z = __builtin_amdgcn_mfma_f32_16x16x32_bf16(qf[ks], kf, z, 0, 0, 0);
      }
      sfr[j] = z;
    }
    __builtin_amdgcn_s_setprio(0);

    float px[4];
#pragma unroll
    for (int r = 0; r < 4; r++)
      px[r] = fmaxf(fmaxf(sfr[0][r], sfr[1][r]), fmaxf(sfr[2][r], sfr[3][r]));
    bool ok = (px[0] <= m[0] + 8.0f) && (px[1] <= m[1] + 8.0f) &&
              (px[2] <= m[2] + 8.0f) && (px[3] <= m[3] + 8.0f);
    if (!__all(ok)) {
#pragma unroll
      for (int r = 0; r < 4; r++) {
        float mx = px[r];
#pragma unroll
        for (int mk = 1; mk < 16; mk <<= 1) mx = fmaxf(mx, __shfl_xor(mx, mk, 64));
        mx = fmaxf(mx, m[r]);
        const float al = __builtin_amdgcn_exp2f(m[r] - mx);
        m[r] = mx;
        ls[r] *= al;
#pragma unroll
        for (int j = 0; j < 4; j++) o[j][r] *= al;
      }
    }

#pragma unroll
    for (int j = 0; j < 4; j++)
#pragma unroll
      for (int r = 0; r < 4; r++) {
        const float p = __builtin_amdgcn_exp2f(sfr[j][r] - m[r]);
        ls[r] += p;
        Pl[wave][lg * 4 + r][j * 16 + lr] = (bf16_t)p;
      }

    __builtin_amdgcn_s_setprio(1);
#pragma unroll
    for (int ks = 0; ks < 2; ks++) {
      bf16x8 pa = *(const bf16x8*)(&Pl[wave][lr][lg * 8 + ks * 32]);
#pragma unroll
      for (int j = 0; j < 4; j++) {
        bf16x8 vb = *(const bf16x8*)(&Vs[buf][(j * 16 + lr) * 64 + ((lg * 8 + ks * 32) ^ sw)]);
        o[j] = __builtin_amdgcn_mfma_f32_16x16x32_bf16(pa, vb, o[j], 0, 0, 0);
      }
    }
    __builtin_amdgcn_s_setprio(0);

    __syncthreads();
  }

#pragma unroll
  for (int r = 0; r < 4; r++)
#pragma unroll
    for (int mk = 1; mk < 16; mk <<= 1) ls[r] += __shfl_xor(ls[r], mk, 64);

  const size_t orow = (size_t)(b * 1024 + qt * 128 + wave * 16 + lg * 4);
#pragma unroll
  for (int j = 0; j < 4; j++)
#pragma unroll
    for (int r = 0; r < 4; r++)
      out[(orow + r) * 512 + h * 64 + j * 16 + lr] = (bf16_t)(o[j][r] / ls[r]);
}

// ------------------------------------------------------------------
// s += pos + ts[step]; p = sigmoid(s . p_w + p_b); ACT halting update.
// Only used for step 0 (later steps fused into k_lnhalt).
// ------------------------------------------------------------------
__global__ __launch_bounds__(256)
void k_poshalt(float* __restrict__ s, bf16_t* __restrict__ xbf,
               const float* __restrict__ pos, const float* __restrict__ ts, int step,
               const float* __restrict__ pw, const float* __restrict__ pb,
               float* __restrict__ hp, float* __restrict__ rem, float* __restrict__ uw,
               const int* __restrict__ flag)
{
  if (*flag) return;
  const int row = blockIdx.x;
  const int l = row & 1023;
  const int t = threadIdx.x;
  const size_t base = (size_t)row * 512;
  float v0 = s[base + t]       + pos[l * 512 + t]       + ts[step * 512 + t];
  float v1 = s[base + 256 + t] + pos[l * 512 + 256 + t] + ts[step * 512 + 256 + t];
  s[base + t] = v0; s[base + 256 + t] = v1;
  xbf[base + t] = (bf16_t)v0; xbf[base + 256 + t] = (bf16_t)v1;

  float d = v0 * pw[t] + v1 * pw[256 + t];
#pragma unroll
  for (int mk = 1; mk < 64; mk <<= 1) d += __shfl_xor(d, mk, 64);
  __shared__ float part[4];
  if ((t & 63) == 0) part[t >> 6] = d;
  __syncthreads();
  if (t == 0) {
    const float z = part[0] + part[1] + part[2] + part[3] + pb[0];
    const float p = 1.0f / (1.0f + expf(-z));
    float h  = (step == 0) ? 0.0f : hp[row];
    float rm = (step == 0) ? 0.0f : rem[row];
    const float still0 = (h < 1.0f) ? 1.0f : 0.0f;
    const float cond = h + p * still0;
    const float nh = (cond > 0.9f) ? still0 : 0.0f;
    const float st = (cond <= 0.9f) ? still0 : 0.0f;
    h += p * st;
    rm += nh * (1.0f - h);
    h += nh * rm;
    hp[row] = h; rem[row] = rm;
    uw[row] = p * st + nh * rm;
  }
}

// ------------------------------------------------------------------
// Post-attn LN: y = LayerNorm(s + tmp); write y fp32 + bf16.
// ------------------------------------------------------------------
__global__ __launch_bounds__(256)
void k_addln1(const float* __restrict__ xa, const float* __restrict__ xb,
              const float* __restrict__ g, const float* __restrict__ be,
              float* __restrict__ yout, bf16_t* __restrict__ ybf,
              const int* __restrict__ flag)
{
  if (*flag) return;
  const int row = blockIdx.x, t = threadIdx.x;
  const size_t base = (size_t)row * 512;
  const float v0 = xa[base + t] + xb[base + t];
  const float v1 = xa[base + 256 + t] + xb[base + 256 + t];
  float s1 = v0 + v1, s2 = v0 * v0 + v1 * v1;
#pragma unroll
  for (int mk = 1; mk < 64; mk <<= 1) { s1 += __shfl_xor(s1, mk, 64); s2 += __shfl_xor(s2, mk, 64); }
  __shared__ float p1[4], p2[4];
  if ((t & 63) == 0) { p1[t >> 6] = s1; p2[t >> 6] = s2; }
  __syncthreads();
  s1 = p1[0] + p1[1] + p1[2] + p1[3];
  s2 = p2[0] + p2[1] + p2[2] + p2[3];
  const float mean = s1 * (1.0f / 512.0f);
  const float var  = s2 * (1.0f / 512.0f) - mean * mean;
  const float ri = rsqrtf(var + 1e-5f);
  const float y0 = (v0 - mean) * ri * g[t]       + be[t];
  const float y1 = (v1 - mean) * ri * g[256 + t] + be[256 + t];
  yout[base + t] = y0; yout[base + 256 + t] = y1;
  ybf[base + t] = (bf16_t)y0; ybf[base + 256 + t] = (bf16_t)y1;
}

// ------------------------------------------------------------------
// Fused bottom-of-step: y = LN(x1 + ffn2); prev = y*uw + prev*(1-uw);
// then NEXT step's pos/ts add + halting gate (poshalt for step+1).
// LAST=true: step 5 — prev update only (s unused afterwards).
// ------------------------------------------------------------------
template <bool LAST>
__global__ __launch_bounds__(256)
void k_lnhalt(const float* __restrict__ xa, const float* __restrict__ xb,
              const float* __restrict__ g, const float* __restrict__ be,
              const float* __restrict__ pos, const float* __restrict__ ts, int nstep,
              const float* __restrict__ pw, const float* __restrict__ pb,
              float* __restrict__ s, bf16_t* __restrict__ xbf,
              float* __restrict__ hp, float* __restrict__ rem, float* __restrict__ uw,
              float* __restrict__ prev, int step, const int* __restrict__ flag)
{
  if (*flag) return;
  const int row = blockIdx.x, t = threadIdx.x;
  const int l = row & 1023;
  const size_t base = (size_t)row * 512;
  const float a0 = xa[base + t] + xb[base + t];
  const float a1 = xa[base + 256 + t] + xb[base + 256 + t];
  float s1 = a0 + a1, s2 = a0 * a0 + a1 * a1;
#pragma unroll
  for (int mk = 1; mk < 64; mk <<= 1) { s1 += __shfl_xor(s1, mk, 64); s2 += __shfl_xor(s2, mk, 64); }
  __shared__ float p1[4], p2[4], pd[4];
  if ((t & 63) == 0) { p1[t >> 6] = s1; p2[t >> 6] = s2; }
  __syncthreads();
  s1 = p1[0] + p1[1] + p1[2] + p1[3];
  s2 = p2[0] + p2[1] + p2[2] + p2[3];
  const float mean = s1 * (1.0f / 512.0f);
  const float var  = s2 * (1.0f / 512.0f) - mean * mean;
  const float ri = rsqrtf(var + 1e-5f);
  const float y0 = (a0 - mean) * ri * g[t]       + be[t];
  const float y1 = (a1 - mean) * ri * g[256 + t] + be[256 + t];

  // prev = y*w + prev*(1-w)
  const float w = uw[row];
  if (step == 0) {
    prev[base + t] = y0 * w; prev[base + 256 + t] = y1 * w;
  } else if (w != 0.0f) {
    const float pv0 = prev[base + t];
    const float pv1 = prev[base + 256 + t];
    prev[base + t]       = y0 * w + pv0 * (1.0f - w);
    prev[base + 256 + t] = y1 * w + pv1 * (1.0f - w);
  }

  if (LAST) return;

  // ---- next step: s = y + pos + ts[nstep]; halting gate ----
  const float v0 = y0 + pos[l * 512 + t]       + ts[nstep * 512 + t];
  const float v1 = y1 + pos[l * 512 + 256 + t] + ts[nstep * 512 + 256 + t];
  s[base + t] = v0; s[base + 256 + t] = v1;
  xbf[base + t] = (bf16_t)v0; xbf[base + 256 + t] = (bf16_t)v1;

  float d = v0 * pw[t] + v1 * pw[256 + t];
#pragma unroll
  for (int mk = 1; mk < 64; mk <<= 1) d += __shfl_xor(d, mk, 64);
  if ((t & 63) == 0) pd[t >> 6] = d;
  __syncthreads();
  if (t == 0) {
    const float z = pd[0] + pd[1] + pd[2] + pd[3] + pb[0];
    const float p = 1.0f / (1.0f + expf(-z));
    float h  = hp[row];
    float rm = rem[row];
    const float still0 = (h < 1.0f) ? 1.0f : 0.0f;
    const float cond = h + p * still0;
    const float nh = (cond > 0.9f) ? still0 : 0.0f;
    const float st = (cond <= 0.9f) ? still0 : 0.0f;
    h += p * st;
    rm += nh * (1.0f - h);
    h += nh * rm;
    hp[row] = h; rem[row] = rm;
    uw[row] = p * st + nh * rm;
  }
}

// ------------------------------------------------------------------
// All-halted detector: flag=1 once min(hp) >= 1 AND max(uw) == 0
// (uw for the upcoming step already consumed-as-zero -> all remaining
// steps provably dead w.r.t. prev).
// ------------------------------------------------------------------
__global__ __launch_bounds__(256)
void k_flag(const float* __restrict__ hp, const float* __restrict__ uw,
            int* __restrict__ flag)
{
  if (*flag) return;
  const int t = threadIdx.x;
  float mn = 1e30f, mxw = 0.0f;
#pragma unroll
  for (int i = 0; i < 4; i++) {
    f32x8 v = *(const f32x8*)(hp + (t + i * 256) * 8);
    f32x8 u = *(const f32x8*)(uw + (t + i * 256) * 8);
#pragma unroll
    for (int q = 0; q < 8; q++) { mn = fminf(mn, v[q]); mxw = fmaxf(mxw, u[q]); }
  }
#pragma unroll
  for (int mk = 1; mk < 64; mk <<= 1) {
    mn = fminf(mn, __shfl_xor(mn, mk, 64));
    mxw = fmaxf(mxw, __shfl_xor(mxw, mk, 64));
  }
  __shared__ float part[4], partw[4];
  if ((t & 63) == 0) { part[t >> 6] = mn; partw[t >> 6] = mxw; }
  __syncthreads();
  if (t == 0) {
    mn = fminf(fminf(part[0], part[1]), fminf(part[2], part[3]));
    mxw = fmaxf(fmaxf(partw[0], partw[1]), fmaxf(partw[2], partw[3]));
    if (mn >= 1.0f && mxw == 0.0f) *flag = 1;
  }
}

__global__ void k_zeroflag(int* __restrict__ flag) { *flag = 0; }

// ------------------------------------------------------------------
__global__ void k_pos_ts(float* __restrict__ pos, float* __restrict__ ts,
                         const int* __restrict__ outer)
{
  const int idx = blockIdx.x * 256 + threadIdx.x;
  const int l = idx >> 9, i = idx & 511;
  const float dt = expf((float)(i & ~1) * (-9.210340371976184f / 512.0f));
  const float a = (float)l * dt;
  pos[idx] = (i & 1) ? cosf(a) : sinf(a);
  if (l < 6) {
    const int gidx = 6 * outer[0] + l;
    const float a2 = (float)gidx * dt;
    ts[l * 512 + i] = (i & 1) ? cosf(a2) : sinf(a2);
  }
}

__global__ void k_f2b(const float* __restrict__ in, bf16_t* __restrict__ out, int n)
{
  const int i = blockIdx.x * 256 + threadIdx.x;
  if (i < n) out[i] = (bf16_t)in[i];
}

__global__ void k_copy(const float* __restrict__ in, float* __restrict__ out, int n)
{
  const int i = blockIdx.x * 256 + threadIdx.x;
  if (i < n) out[i] = in[i];
}

// ------------------------------------------------------------------
extern "C" void kernel_launch(void* const* d_in, const int* in_sizes, int n_in,
                              void* d_out, int out_size, void* d_ws, size_t ws_size,
                              hipStream_t stream)
{
  const float* state = (const float*)d_in[0];
  const int*   outer = (const int*)d_in[1];
  const float* p_w   = (const float*)d_in[2];
  const float* p_b   = (const float*)d_in[3];
  const float* wq = (const float*)d_in[4];
  const float* bq = (const float*)d_in[5];
  const float* wk = (const float*)d_in[6];
  const float* bk = (const float*)d_in[7];
  const float* wv = (const float*)d_in[8];
  const float* bv = (const float*)d_in[9];
  const float* wo = (const float*)d_in[10];
  const float* bo = (const float*)d_in[11];
  const float* w1 = (const float*)d_in[12];
  const float* b1 = (const float*)d_in[13];
  const float* w2 = (const float*)d_in[14];
  const float* b2 = (const float*)d_in[15];
  const float* ln1g = (const float*)d_in[16];
  const float* ln1b = (const float*)d_in[17];
  const float* ln2g = (const float*)d_in[18];
  const float* ln2b = (const float*)d_in[19];
  float* prev = (float*)d_out;

  char* cur = (char*)d_ws;
  auto take = [&](size_t n) { char* p = cur; cur += (n + 255) & ~(size_t)255; return p; };
  float*  pos   = (float*) take((size_t)1024 * 512 * 4);
  float*  ts    = (float*) take(6 * 512 * 4);
  bf16_t* wqkvB = (bf16_t*)take((size_t)1536 * 512 * 2);
  bf16_t* woB   = (bf16_t*)take((size_t)512 * 512 * 2);
  bf16_t* w1B   = (bf16_t*)take((size_t)2048 * 512 * 2);
  bf16_t* w2B   = (bf16_t*)take((size_t)512 * 2048 * 2);
  float*  bqkv  = (float*) take(1536 * 4);
  float*  s     = (float*) take((size_t)8192 * 512 * 4);
  float*  x1    = (float*) take((size_t)8192 * 512 * 4);
  bf16_t* x1B   = (bf16_t*)take((size_t)8192 * 512 * 2);
  float*  tmp   = (float*) take((size_t)8192 * 512 * 4);   // also hosts vt (bf16) while dead
  bf16_t* attnO = (bf16_t*)take((size_t)8192 * 512 * 2);
  float*  hp    = (float*) take(8192 * 4);
  float*  rem   = (float*) take(8192 * 4);
  float*  uw    = (float*) take(8192 * 4);
  int*    flag  = (int*)   take(4);
  char*   region = take((size_t)8192 * 2048 * 2);
  bf16_t* xB  = (bf16_t*)region;
  bf16_t* qkv = (bf16_t*)(region + (size_t)8192 * 512 * 2);
  bf16_t* hB  = (bf16_t*)region;
  bf16_t* vt  = (bf16_t*)tmp;

  // ---- precompute ----
  k_zeroflag<<<dim3(1), dim3(1), 0, stream>>>(flag);
  k_pos_ts<<<dim3(2048), dim3(256), 0, stream>>>(pos, ts, outer);
  k_f2b<<<dim3(1024), dim3(256), 0, stream>>>(wq, wqkvB,               512 * 512);
  k_f2b<<<dim3(1024), dim3(256), 0, stream>>>(wk, wqkvB + 512 * 512,   512 * 512);
  k_f2b<<<dim3(1024), dim3(256), 0, stream>>>(wv, wqkvB + 1024 * 512,  512 * 512);
  k_f2b<<<dim3(1024), dim3(256), 0, stream>>>(wo, woB,                 512 * 512);
  k_f2b<<<dim3(4096), dim3(256), 0, stream>>>(w1, w1B,                 2048 * 512);
  k_f2b<<<dim3(4096), dim3(256), 0, stream>>>(w2, w2B,                 512 * 2048);
  k_copy<<<dim3(2), dim3(256), 0, stream>>>(bq, bqkv,        512);
  k_copy<<<dim3(2), dim3(256), 0, stream>>>(bk, bqkv + 512,  512);
  k_copy<<<dim3(2), dim3(256), 0, stream>>>(bv, bqkv + 1024, 512);
  k_copy<<<dim3(16384), dim3(256), 0, stream>>>(state, s, 8192 * 512);

  // step 0 top: pos/ts add + halting gate
  k_poshalt<<<dim3(8192), dim3(256), 0, stream>>>(s, xB, pos, ts, 0, p_w, p_b, hp, rem, uw, flag);

  // ---- 6 hops ----
  for (int step = 0; step < 6; step++) {
    gemm_bt<false, true ><<<dim3(64, 12), dim3(256), 0, stream>>>(xB, wqkvB, bqkv, (void*)qkv, 8192, 1536, 512, flag);
    k_vtrans<<<dim3(64, 16), dim3(256), 0, stream>>>(qkv, vt, flag);
    k_attn<<<dim3(64, 8), dim3(512), 0, stream>>>(qkv, vt, attnO, flag);
    gemm_bt512<false, false><<<dim3(64, 4), dim3(512), 0, stream>>>(attnO, woB, bo, (void*)tmp, 8192, 512, 512, flag);
    k_addln1<<<dim3(8192), dim3(256), 0, stream>>>(s, tmp, ln1g, ln1b, x1, x1B, flag);
    gemm_bt<true,  true ><<<dim3(64, 16), dim3(256), 0, stream>>>(x1B, w1B, b1, (void*)hB, 8192, 2048, 512, flag);
    gemm_bt512<false, false><<<dim3(64, 4), dim3(512), 0, stream>>>(hB, w2B, b2, (void*)tmp, 8192, 512, 2048, flag);
    if (step < 5) {
      k_lnhalt<false><<<dim3(8192), dim3(256), 0, stream>>>(x1, tmp, ln2g, ln2b, pos, ts, step + 1,
                                                            p_w, p_b, s, xB, hp, rem, uw, prev, step, flag);
      k_flag<<<dim3(1), dim3(256), 0, stream>>>(hp, uw, flag);
    } else {
      k_lnhalt<true><<<dim3(8192), dim3(256), 0, stream>>>(x1, tmp, ln2g, ln2b, pos, ts, 0,
                                                           p_w, p_b, s, xB, hp, rem, uw, prev, step, flag);
    }
  }
}

// Round 8
// 721.354 us; speedup vs baseline: 1.0962x; 1.0572x over previous
//
#include <hip/hip_runtime.h>
#include <hip/hip_bf16.h>

typedef __bf16 bf16_t;
typedef __bf16 bf16x8 __attribute__((ext_vector_type(8)));
typedef float  f32x4  __attribute__((ext_vector_type(4)));
typedef float  f32x8  __attribute__((ext_vector_type(8)));

static __device__ __forceinline__ void gload_lds16(const void* g, void* l) {
  __builtin_amdgcn_global_load_lds((const __attribute__((address_space(1))) void*)g,
                                   (__attribute__((address_space(3))) void*)l, 16, 0, 0);
}

// LDS chunk swizzle for [rows][32] bf16 tiles: chunk' = chunk ^ ((row>>1)&3).

// ------------------------------------------------------------------
// GEMM  C = A*B^T (+bias, relu opt). 128x128 tile, BK=32, 4 waves,
// 2-phase dbuf. For QKV (N=1536, 3 blk/CU) / FFN1 (N=2048, 4 blk/CU).
// ------------------------------------------------------------------
template <bool RELU, bool OUTBF>
__global__ __launch_bounds__(256)
void gemm_bt(const bf16_t* __restrict__ A, const bf16_t* __restrict__ B,
             const float* __restrict__ bias, void* __restrict__ Cv,
             int M, int N, int K, const int* __restrict__ flag)
{
  if (*flag) return;
  __shared__ bf16_t As[2][128 * 32];
  __shared__ bf16_t Bs[2][128 * 32];
  const int tid = threadIdx.x;
  const int lane = tid & 63, wave = tid >> 6;
  const int wr = (wave >> 1) * 64, wc = (wave & 1) * 64;
  const int lr = lane & 15, lg = lane >> 4;
  const int m0 = blockIdx.x * 128, n0 = blockIdx.y * 128;

  const bf16_t* Ab = A + (size_t)m0 * K;
  const bf16_t* Bb = B + (size_t)n0 * K;

  f32x4 acc[4][4] = {};

  const int r0 = tid >> 2;
  const int c0 = (((tid & 3) ^ ((r0 >> 1) & 3)) * 8);
  const int lsw = (lg ^ ((lr >> 1) & 3)) * 8;

  auto stage = [&](int buf, int kk) {
    gload_lds16(Ab + (size_t)r0 * K + kk + c0,        &As[buf][tid * 8]);
    gload_lds16(Bb + (size_t)r0 * K + kk + c0,        &Bs[buf][tid * 8]);
    gload_lds16(Ab + (size_t)(r0 + 64) * K + kk + c0, &As[buf][(tid + 256) * 8]);
    gload_lds16(Bb + (size_t)(r0 + 64) * K + kk + c0, &Bs[buf][(tid + 256) * 8]);
  };

  stage(0, 0);
  __syncthreads();

  const int nk = K >> 5;
  for (int t = 0; t < nk; ++t) {
    const int buf = t & 1;
    if (t + 1 < nk) stage(buf ^ 1, (t + 1) * 32);
    bf16x8 af[4], bfr[4];
#pragma unroll
    for (int i = 0; i < 4; i++) af[i]  = *(const bf16x8*)(&As[buf][(wr + i * 16 + lr) * 32 + lsw]);
#pragma unroll
    for (int j = 0; j < 4; j++) bfr[j] = *(const bf16x8*)(&Bs[buf][(wc + j * 16 + lr) * 32 + lsw]);
#pragma unroll
    for (int i = 0; i < 4; i++)
#pragma unroll
      for (int j = 0; j < 4; j++)
        acc[i][j] = __builtin_amdgcn_mfma_f32_16x16x32_bf16(af[i], bfr[j], acc[i][j], 0, 0, 0);
    __syncthreads();
  }

  const int rg = (lane >> 4) * 4;
#pragma unroll
  for (int j = 0; j < 4; j++) {
    const int col = n0 + wc + j * 16 + lr;
    const float bv = bias ? bias[col] : 0.0f;
#pragma unroll
    for (int i = 0; i < 4; i++) {
#pragma unroll
      for (int r = 0; r < 4; r++) {
        const int row = m0 + wr + i * 16 + rg + r;
        float v = acc[i][j][r] + bv;
        if (RELU) v = fmaxf(v, 0.0f);
        if (OUTBF) ((bf16_t*)Cv)[(size_t)row * N + col] = (bf16_t)v;
        else       ((float*)Cv)[(size_t)row * N + col]  = v;
      }
    }
  }
}

// ------------------------------------------------------------------
// GEMM 128x128, 512 threads / 8 waves (2x4), wave = 64x32, 2-phase
// dbuf, fp32 output, optional split-K via gridDim.z (each z-half
// writes its own output buffer; bias folded into half 0 only).
// For N=512 outputs: O-proj (z=1), FFN2 (z=2 -> 2 blocks/CU).
// ------------------------------------------------------------------
__global__ __launch_bounds__(512)
void gemm_bt512(const bf16_t* __restrict__ A, const bf16_t* __restrict__ B,
                const float* __restrict__ bias, float* __restrict__ Cv0,
                float* __restrict__ Cv1, int M, int N, int Kfull, int Keff,
                const int* __restrict__ flag)
{
  if (*flag) return;
  __shared__ bf16_t As[2][128 * 32];
  __shared__ bf16_t Bs[2][128 * 32];
  const int tid = threadIdx.x;
  const int lane = tid & 63, wave = tid >> 6;
  const int wr = (wave >> 2) * 64, wc = (wave & 3) * 32;
  const int lr = lane & 15, lg = lane >> 4;
  const int m0 = blockIdx.x * 128, n0 = blockIdx.y * 128;
  const int kb = blockIdx.z;

  const bf16_t* Ab = A + (size_t)m0 * Kfull + (size_t)kb * Keff;
  const bf16_t* Bb = B + (size_t)n0 * Kfull + (size_t)kb * Keff;
  float* C = kb ? Cv1 : Cv0;

  f32x4 acc[4][2] = {};

  const int r0 = tid >> 2;
  const int c0 = (((tid & 3) ^ ((r0 >> 1) & 3)) * 8);
  const int lsw = (lg ^ ((lr >> 1) & 3)) * 8;

  auto stage = [&](int buf, int kk) {
    gload_lds16(Ab + (size_t)r0 * Kfull + kk + c0, &As[buf][tid * 8]);
    gload_lds16(Bb + (size_t)r0 * Kfull + kk + c0, &Bs[buf][tid * 8]);
  };

  stage(0, 0);
  __syncthreads();

  const int nk = Keff >> 5;
  for (int t = 0; t < nk; ++t) {
    const int buf = t & 1;
    if (t + 1 < nk) stage(buf ^ 1, (t + 1) * 32);
    bf16x8 af[4], bfr[2];
#pragma unroll
    for (int i = 0; i < 4; i++) af[i]  = *(const bf16x8*)(&As[buf][(wr + i * 16 + lr) * 32 + lsw]);
#pragma unroll
    for (int j = 0; j < 2; j++) bfr[j] = *(const bf16x8*)(&Bs[buf][(wc + j * 16 + lr) * 32 + lsw]);
#pragma unroll
    for (int i = 0; i < 4; i++)
#pragma unroll
      for (int j = 0; j < 2; j++)
        acc[i][j] = __builtin_amdgcn_mfma_f32_16x16x32_bf16(af[i], bfr[j], acc[i][j], 0, 0, 0);
    __syncthreads();
  }

  const int rg = (lane >> 4) * 4;
#pragma unroll
  for (int j = 0; j < 2; j++) {
    const int col = n0 + wc + j * 16 + lr;
    const float bv = (bias && kb == 0) ? bias[col] : 0.0f;
#pragma unroll
    for (int i = 0; i < 4; i++) {
#pragma unroll
      for (int r = 0; r < 4; r++) {
        const int row = m0 + wr + i * 16 + rg + r;
        C[(size_t)row * N + col] = acc[i][j][r] + bv;
      }
    }
  }
}

// ------------------------------------------------------------------
// V transpose: per (b,h), V (1024 keys x 64 d) -> VT (64 d x 1024 keys).
// ------------------------------------------------------------------
__global__ __launch_bounds__(256)
void k_vtrans(const bf16_t* __restrict__ qkv, bf16_t* __restrict__ vt,
              const int* __restrict__ flag)
{
  if (*flag) return;
  __shared__ bf16_t T[64][72];
  const int bh = blockIdx.x, kt = blockIdx.y;
  const int b = bh >> 3, h = bh & 7;
  const int t = threadIdx.x;
  const bf16_t* Vb = qkv + ((size_t)(b * 1024 + kt * 64)) * 1536 + 1024 + h * 64;
  {
    const int c = t & 7, r = t >> 3;
    *(bf16x8*)&T[r][c * 8]      = *(const bf16x8*)(Vb + (size_t)r * 1536 + c * 8);
    *(bf16x8*)&T[r + 32][c * 8] = *(const bf16x8*)(Vb + (size_t)(r + 32) * 1536 + c * 8);
  }
  __syncthreads();
  bf16_t* O = vt + ((size_t)bh * 64) * 1024 + (size_t)kt * 64;
  {
    const int d = t >> 2, kc = t & 3;
#pragma unroll
    for (int half = 0; half < 2; half++) {
      const int k0 = (kc + 4 * half) * 8;
      bf16x8 v;
#pragma unroll
      for (int u = 0; u < 8; u++) v[u] = T[k0 + u][d];
      *(bf16x8*)(O + (size_t)d * 1024 + k0) = v;
    }
  }
}

// ------------------------------------------------------------------
// Flash attention v5 (swapped QK^T): compute S^T = mfma(K,Q) so each
// lane's 16 scores belong to ONE q-row (q = wave*16 + lane&15) ->
// scalar m/ls, 2-shuffle rescale (rare, defer-max), key-contiguous P
// packing via v_cvt_pk_bf16_f32 + ds_write_b64. PV unchanged.
// ------------------------------------------------------------------
__global__ __launch_bounds__(512)
void k_attn(const bf16_t* __restrict__ qkv, const bf16_t* __restrict__ vt,
            bf16_t* __restrict__ out, const int* __restrict__ flag)
{
  if (*flag) return;
  const int bh = blockIdx.x;
  const int qt = blockIdx.y;
  const int b = bh >> 3, h = bh & 7;
  const int tid = threadIdx.x, lane = tid & 63, wave = tid >> 6;
  const int lr = lane & 15, lg = lane >> 4;

  __shared__ bf16_t Ks[2][4096];
  __shared__ bf16_t Vs[2][4096];
  __shared__ bf16_t Pl[8][16][68];

  const size_t RS = 1536;
  const bf16_t* Qb = qkv + ((size_t)(b * 1024 + qt * 128)) * RS + h * 64;
  const bf16_t* Kb = qkv + ((size_t)(b * 1024)) * RS + 512 + h * 64;
  const bf16_t* Vt = vt + (size_t)bh * 64 * 1024;

  const float SC = 0.125f * 1.4426950408889634f;
  bf16x8 qf[2];
#pragma unroll
  for (int ks = 0; ks < 2; ks++) {
    bf16x8 q = *(const bf16x8*)(Qb + (size_t)(wave * 16 + lr) * RS + lg * 8 + ks * 32);
#pragma unroll
    for (int u = 0; u < 8; u++) q[u] = (bf16_t)((float)q[u] * SC);
    qf[ks] = q;
  }

  f32x4 o[4] = {};
  float m_ = -1e30f, ls_ = 0.0f;     // per-lane: q-row = wave*16 + lr

  auto stage = [&](int buf, int kv) {
    const int c = tid;
    const int r = c >> 3;
    const int ce = (c & 7) * 8;
    const int cs = ce ^ ((r & 7) << 3);
    gload_lds16(Kb + (size_t)(kv * 64 + r) * RS + cs, &Ks[buf][c * 8]);
    gload_lds16(Vt + (size_t)r * 1024 + kv * 64 + cs, &Vs[buf][c * 8]);
  };

  stage(0, 0);
  __syncthreads();

  const int sw = (lr & 7) << 3;

  for (int kv = 0; kv < 16; kv++) {
    const int buf = kv & 1;
    if (kv < 15) stage(buf ^ 1, kv + 1);

    // ---- S^T = K Q^T: sfr[j][r] = S[key = kv*64+j*16+lg*4+r][q = wave*16+lr]
    f32x4 sfr[4];
    __builtin_amdgcn_s_setprio(1);
#pragma unroll
    for (int j = 0; j < 4; j++) {
      f32x4 z = {};
#pragma unroll
      for (int ks = 0; ks < 2; ks++) {
        bf16x8 kf = *(const bf16x8*)(&Ks[buf][(j * 16 + lr) * 64 + ((lg * 8 + ks * 32) ^ sw)]);
        z = __builtin_amdgcn_mfma_f32_16x16x32_bf16(kf, qf[ks], z, 0, 0, 0);
      }
      sfr[j] = z;
    }
    __builtin_amdgcn_s_setprio(0);

    // ---- defer-max online softmax (scalar per-lane state) ----
    float px = sfr[0][0];
#pragma unroll
    for (int j = 0; j < 4; j++)
#pragma unroll
      for (int r = 0; r < 4; r++) px = fmaxf(px, sfr[j][r]);
    if (!__all(px <= m_ + 8.0f)) {
      float mx = fmaxf(px, __shfl_xor(px, 16, 64));
      mx = fmaxf(mx, __shfl_xor(mx, 32, 64));
      mx = fmaxf(mx, m_);
      const float al = __builtin_amdgcn_exp2f(m_ - mx);
      m_ = mx;
      ls_ *= al;
      float aq[4];
#pragma unroll
      for (int r = 0; r < 4; r++) aq[r] = __shfl(al, lg * 4 + r, 64);
#pragma unroll
      for (int j = 0; j < 4; j++)
#pragma unroll
        for (int r = 0; r < 4; r++) o[j][r] *= aq[r];
    }

    // ---- P = exp2(S - m); pack 4 key-contiguous bf16 -> ds_write_b64 ----
    float ps = 0.0f;
#pragma unroll
    for (int j = 0; j < 4; j++) {
      const float p0 = __builtin_amdgcn_exp2f(sfr[j][0] - m_);
      const float p1 = __builtin_amdgcn_exp2f(sfr[j][1] - m_);
      const float p2 = __builtin_amdgcn_exp2f(sfr[j][2] - m_);
      const float p3 = __builtin_amdgcn_exp2f(sfr[j][3] - m_);
      ps += (p0 + p1) + (p2 + p3);
      unsigned lo, hi;
      asm("v_cvt_pk_bf16_f32 %0, %1, %2" : "=v"(lo) : "v"(p0), "v"(p1));
      asm("v_cvt_pk_bf16_f32 %0, %1, %2" : "=v"(hi) : "v"(p2), "v"(p3));
      uint2 w; w.x = lo; w.y = hi;
      *(uint2*)(&Pl[wave][lr][j * 16 + lg * 4]) = w;
    }
    ls_ += ps;

    // ---- O += P * V ----
    __builtin_amdgcn_s_setprio(1);
#pragma unroll
    for (int ks = 0; ks < 2; ks++) {
      bf16x8 pa = *(const bf16x8*)(&Pl[wave][lr][lg * 8 + ks * 32]);
#pragma unroll
      for (int j = 0; j < 4; j++) {
        bf16x8 vb = *(const bf16x8*)(&Vs[buf][(j * 16 + lr) * 64 + ((lg * 8 + ks * 32) ^ sw)]);
        o[j] = __builtin_amdgcn_mfma_f32_16x16x32_bf16(pa, vb, o[j], 0, 0, 0);
      }
    }
    __builtin_amdgcn_s_setprio(0);

    __syncthreads();
  }

  // row-sum totals: sum across the 4 lanes sharing q, then gather per out-row
  ls_ += __shfl_xor(ls_, 16, 64);
  ls_ += __shfl_xor(ls_, 32, 64);
  float lsq[4];
#pragma unroll
  for (int r = 0; r < 4; r++) lsq[r] = __shfl(ls_, lg * 4 + r, 64);

  const size_t orow = (size_t)(b * 1024 + qt * 128 + wave * 16 + lg * 4);
#pragma unroll
  for (int j = 0; j < 4; j++)
#pragma unroll
    for (int r = 0; r < 4; r++)
      out[(orow + r) * 512 + h * 64 + j * 16 + lr] = (bf16_t)(o[j][r] / lsq[r]);
}

// ------------------------------------------------------------------
// s += pos + ts[step]; p = sigmoid(s . p_w + p_b); ACT halting update.
// Only used for step 0 (later steps fused into k_lnhalt).
// ------------------------------------------------------------------
__global__ __launch_bounds__(256)
void k_poshalt(float* __restrict__ s, bf16_t* __restrict__ xbf,
               const float* __restrict__ pos, const float* __restrict__ ts, int step,
               const float* __restrict__ pw, const float* __restrict__ pb,
               float* __restrict__ hp, float* __restrict__ rem, float* __restrict__ uw,
               const int* __restrict__ flag)
{
  if (*flag) return;
  const int row = blockIdx.x;
  const int l = row & 1023;
  const int t = threadIdx.x;
  const size_t base = (size_t)row * 512;
  float v0 = s[base + t]       + pos[l * 512 + t]       + ts[step * 512 + t];
  float v1 = s[base + 256 + t] + pos[l * 512 + 256 + t] + ts[step * 512 + 256 + t];
  s[base + t] = v0; s[base + 256 + t] = v1;
  xbf[base + t] = (bf16_t)v0; xbf[base + 256 + t] = (bf16_t)v1;

  float d = v0 * pw[t] + v1 * pw[256 + t];
#pragma unroll
  for (int mk = 1; mk < 64; mk <<= 1) d += __shfl_xor(d, mk, 64);
  __shared__ float part[4];
  if ((t & 63) == 0) part[t >> 6] = d;
  __syncthreads();
  if (t == 0) {
    const float z = part[0] + part[1] + part[2] + part[3] + pb[0];
    const float p = 1.0f / (1.0f + expf(-z));
    float h  = (step == 0) ? 0.0f : hp[row];
    float rm = (step == 0) ? 0.0f : rem[row];
    const float still0 = (h < 1.0f) ? 1.0f : 0.0f;
    const float cond = h + p * still0;
    const float nh = (cond > 0.9f) ? still0 : 0.0f;
    const float st = (cond <= 0.9f) ? still0 : 0.0f;
    h += p * st;
    rm += nh * (1.0f - h);
    h += nh * rm;
    hp[row] = h; rem[row] = rm;
    uw[row] = p * st + nh * rm;
  }
}

// ------------------------------------------------------------------
// Post-attn LN: y = LayerNorm(s + tmp); write y fp32 + bf16.
// ------------------------------------------------------------------
__global__ __launch_bounds__(256)
void k_addln1(const float* __restrict__ xa, const float* __restrict__ xb,
              const float* __restrict__ g, const float* __restrict__ be,
              float* __restrict__ yout, bf16_t* __restrict__ ybf,
              const int* __restrict__ flag)
{
  if (*flag) return;
  const int row = blockIdx.x, t = threadIdx.x;
  const size_t base = (size_t)row * 512;
  const float v0 = xa[base + t] + xb[base + t];
  const float v1 = xa[base + 256 + t] + xb[base + 256 + t];
  float s1 = v0 + v1, s2 = v0 * v0 + v1 * v1;
#pragma unroll
  for (int mk = 1; mk < 64; mk <<= 1) { s1 += __shfl_xor(s1, mk, 64); s2 += __shfl_xor(s2, mk, 64); }
  __shared__ float p1[4], p2[4];
  if ((t & 63) == 0) { p1[t >> 6] = s1; p2[t >> 6] = s2; }
  __syncthreads();
  s1 = p1[0] + p1[1] + p1[2] + p1[3];
  s2 = p2[0] + p2[1] + p2[2] + p2[3];
  const float mean = s1 * (1.0f / 512.0f);
  const float var  = s2 * (1.0f / 512.0f) - mean * mean;
  const float ri = rsqrtf(var + 1e-5f);
  const float y0 = (v0 - mean) * ri * g[t]       + be[t];
  const float y1 = (v1 - mean) * ri * g[256 + t] + be[256 + t];
  yout[base + t] = y0; yout[base + 256 + t] = y1;
  ybf[base + t] = (bf16_t)y0; ybf[base + 256 + t] = (bf16_t)y1;
}

// ------------------------------------------------------------------
// Fused bottom-of-step: y = LN(x1 + tmp + s_partial); prev update;
// then NEXT step's pos/ts add + halting gate. s doubles as FFN2's
// split-K half-1 partial on input and the new state on output
// (per-thread read-then-write of identical addresses -> safe).
// ------------------------------------------------------------------
template <bool LAST>
__global__ __launch_bounds__(256)
void k_lnhalt(const float* __restrict__ xa, const float* __restrict__ xb,
              const float* __restrict__ g, const float* __restrict__ be,
              const float* __restrict__ pos, const float* __restrict__ ts, int nstep,
              const float* __restrict__ pw, const float* __restrict__ pb,
              float* s, bf16_t* __restrict__ xbf,
              float* __restrict__ hp, float* __restrict__ rem, float* __restrict__ uw,
              float* __restrict__ prev, int step, const int* __restrict__ flag)
{
  if (*flag) return;
  const int row = blockIdx.x, t = threadIdx.x;
  const int l = row & 1023;
  const size_t base = (size_t)row * 512;
  const float a0 = xa[base + t]       + xb[base + t]       + s[base + t];
  const float a1 = xa[base + 256 + t] + xb[base + 256 + t] + s[base + 256 + t];
  float s1 = a0 + a1, s2 = a0 * a0 + a1 * a1;
#pragma unroll
  for (int mk = 1; mk < 64; mk <<= 1) { s1 += __shfl_xor(s1, mk, 64); s2 += __shfl_xor(s2, mk, 64); }
  __shared__ float p1[4], p2[4], pd[4];
  if ((t & 63) == 0) { p1[t >> 6] = s1; p2[t >> 6] = s2; }
  __syncthreads();
  s1 = p1[0] + p1[1] + p1[2] + p1[3];
  s2 = p2[0] + p2[1] + p2[2] + p2[3];
  const float mean = s1 * (1.0f / 512.0f);
  const float var  = s2 * (1.0f / 512.0f) - mean * mean;
  const float ri = rsqrtf(var + 1e-5f);
  const float y0 = (a0 - mean) * ri * g[t]       + be[t];
  const float y1 = (a1 - mean) * ri * g[256 + t] + be[256 + t];

  const float w = uw[row];
  if (step == 0) {
    prev[base + t] = y0 * w; prev[base + 256 + t] = y1 * w;
  } else if (w != 0.0f) {
    const float pv0 = prev[base + t];
    const float pv1 = prev[base + 256 + t];
    prev[base + t]       = y0 * w + pv0 * (1.0f - w);
    prev[base + 256 + t] = y1 * w + pv1 * (1.0f - w);
  }

  if (LAST) return;

  const float v0 = y0 + pos[l * 512 + t]       + ts[nstep * 512 + t];
  const float v1 = y1 + pos[l * 512 + 256 + t] + ts[nstep * 512 + 256 + t];
  s[base + t] = v0; s[base + 256 + t] = v1;
  xbf[base + t] = (bf16_t)v0; xbf[base + 256 + t] = (bf16_t)v1;

  float d = v0 * pw[t] + v1 * pw[256 + t];
#pragma unroll
  for (int mk = 1; mk < 64; mk <<= 1) d += __shfl_xor(d, mk, 64);
  if ((t & 63) == 0) pd[t >> 6] = d;
  __syncthreads();
  if (t == 0) {
    const float z = pd[0] + pd[1] + pd[2] + pd[3] + pb[0];
    const float p = 1.0f / (1.0f + expf(-z));
    float h  = hp[row];
    float rm = rem[row];
    const float still0 = (h < 1.0f) ? 1.0f : 0.0f;
    const float cond = h + p * still0;
    const float nh = (cond > 0.9f) ? still0 : 0.0f;
    const float st = (cond <= 0.9f) ? still0 : 0.0f;
    h += p * st;
    rm += nh * (1.0f - h);
    h += nh * rm;
    hp[row] = h; rem[row] = rm;
    uw[row] = p * st + nh * rm;
  }
}

// ------------------------------------------------------------------
// All-halted detector: flag=1 once min(hp) >= 1 AND max(uw) == 0.
// ------------------------------------------------------------------
__global__ __launch_bounds__(256)
void k_flag(const float* __restrict__ hp, const float* __restrict__ uw,
            int* __restrict__ flag)
{
  if (*flag) return;
  const int t = threadIdx.x;
  float mn = 1e30f, mxw = 0.0f;
#pragma unroll
  for (int i = 0; i < 4; i++) {
    f32x8 v = *(const f32x8*)(hp + (t + i * 256) * 8);
    f32x8 u = *(const f32x8*)(uw + (t + i * 256) * 8);
#pragma unroll
    for (int q = 0; q < 8; q++) { mn = fminf(mn, v[q]); mxw = fmaxf(mxw, u[q]); }
  }
#pragma unroll
  for (int mk = 1; mk < 64; mk <<= 1) {
    mn = fminf(mn, __shfl_xor(mn, mk, 64));
    mxw = fmaxf(mxw, __shfl_xor(mxw, mk, 64));
  }
  __shared__ float part[4], partw[4];
  if ((t & 63) == 0) { part[t >> 6] = mn; partw[t >> 6] = mxw; }
  __syncthreads();
  if (t == 0) {
    mn = fminf(fminf(part[0], part[1]), fminf(part[2], part[3]));
    mxw = fmaxf(fmaxf(partw[0], partw[1]), fmaxf(partw[2], partw[3]));
    if (mn >= 1.0f && mxw == 0.0f) *flag = 1;
  }
}

__global__ void k_zeroflag(int* __restrict__ flag) { *flag = 0; }

// ------------------------------------------------------------------
__global__ void k_pos_ts(float* __restrict__ pos, float* __restrict__ ts,
                         const int* __restrict__ outer)
{
  const int idx = blockIdx.x * 256 + threadIdx.x;
  const int l = idx >> 9, i = idx & 511;
  const float dt = expf((float)(i & ~1) * (-9.210340371976184f / 512.0f));
  const float a = (float)l * dt;
  pos[idx] = (i & 1) ? cosf(a) : sinf(a);
  if (l < 6) {
    const int gidx = 6 * outer[0] + l;
    const float a2 = (float)gidx * dt;
    ts[l * 512 + i] = (i & 1) ? cosf(a2) : sinf(a2);
  }
}

__global__ void k_f2b(const float* __restrict__ in, bf16_t* __restrict__ out, int n)
{
  const int i = blockIdx.x * 256 + threadIdx.x;
  if (i < n) out[i] = (bf16_t)in[i];
}

__global__ void k_copy(const float* __restrict__ in, float* __restrict__ out, int n)
{
  const int i = blockIdx.x * 256 + threadIdx.x;
  if (i < n) out[i] = in[i];
}

// ------------------------------------------------------------------
extern "C" void kernel_launch(void* const* d_in, const int* in_sizes, int n_in,
                              void* d_out, int out_size, void* d_ws, size_t ws_size,
                              hipStream_t stream)
{
  const float* state = (const float*)d_in[0];
  const int*   outer = (const int*)d_in[1];
  const float* p_w   = (const float*)d_in[2];
  const float* p_b   = (const float*)d_in[3];
  const float* wq = (const float*)d_in[4];
  const float* bq = (const float*)d_in[5];
  const float* wk = (const float*)d_in[6];
  const float* bk = (const float*)d_in[7];
  const float* wv = (const float*)d_in[8];
  const float* bv = (const float*)d_in[9];
  const float* wo = (const float*)d_in[10];
  const float* bo = (const float*)d_in[11];
  const float* w1 = (const float*)d_in[12];
  const float* b1 = (const float*)d_in[13];
  const float* w2 = (const float*)d_in[14];
  const float* b2 = (const float*)d_in[15];
  const float* ln1g = (const float*)d_in[16];
  const float* ln1b = (const float*)d_in[17];
  const float* ln2g = (const float*)d_in[18];
  const float* ln2b = (const float*)d_in[19];
  float* prev = (float*)d_out;

  char* cur = (char*)d_ws;
  auto take = [&](size_t n) { char* p = cur; cur += (n + 255) & ~(size_t)255; return p; };
  float*  pos   = (float*) take((size_t)1024 * 512 * 4);
  float*  ts    = (float*) take(6 * 512 * 4);
  bf16_t* wqkvB = (bf16_t*)take((size_t)1536 * 512 * 2);
  bf16_t* woB   = (bf16_t*)take((size_t)512 * 512 * 2);
  bf16_t* w1B   = (bf16_t*)take((size_t)2048 * 512 * 2);
  bf16_t* w2B   = (bf16_t*)take((size_t)512 * 2048 * 2);
  float*  bqkv  = (float*) take(1536 * 4);
  float*  s     = (float*) take((size_t)8192 * 512 * 4);  // state; also FFN2 split-K half-1 partial
  float*  x1    = (float*) take((size_t)8192 * 512 * 4);
  bf16_t* x1B   = (bf16_t*)take((size_t)8192 * 512 * 2);
  float*  tmp   = (float*) take((size_t)8192 * 512 * 4);  // also hosts vt (bf16) while dead
  bf16_t* attnO = (bf16_t*)take((size_t)8192 * 512 * 2);
  float*  hp    = (float*) take(8192 * 4);
  float*  rem   = (float*) take(8192 * 4);
  float*  uw    = (float*) take(8192 * 4);
  int*    flag  = (int*)   take(4);
  char*   region = take((size_t)8192 * 2048 * 2);
  bf16_t* xB  = (bf16_t*)region;
  bf16_t* qkv = (bf16_t*)(region + (size_t)8192 * 512 * 2);
  bf16_t* hB  = (bf16_t*)region;
  bf16_t* vt  = (bf16_t*)tmp;

  // ---- precompute ----
  k_zeroflag<<<dim3(1), dim3(1), 0, stream>>>(flag);
  k_pos_ts<<<dim3(2048), dim3(256), 0, stream>>>(pos, ts, outer);
  k_f2b<<<dim3(1024), dim3(256), 0, stream>>>(wq, wqkvB,               512 * 512);
  k_f2b<<<dim3(1024), dim3(256), 0, stream>>>(wk, wqkvB + 512 * 512,   512 * 512);
  k_f2b<<<dim3(1024), dim3(256), 0, stream>>>(wv, wqkvB + 1024 * 512,  512 * 512);
  k_f2b<<<dim3(1024), dim3(256), 0, stream>>>(wo, woB,                 512 * 512);
  k_f2b<<<dim3(4096), dim3(256), 0, stream>>>(w1, w1B,                 2048 * 512);
  k_f2b<<<dim3(4096), dim3(256), 0, stream>>>(w2, w2B,                 512 * 2048);
  k_copy<<<dim3(2), dim3(256), 0, stream>>>(bq, bqkv,        512);
  k_copy<<<dim3(2), dim3(256), 0, stream>>>(bk, bqkv + 512,  512);
  k_copy<<<dim3(2), dim3(256), 0, stream>>>(bv, bqkv + 1024, 512);
  k_copy<<<dim3(16384), dim3(256), 0, stream>>>(state, s, 8192 * 512);

  // step 0 top: pos/ts add + halting gate
  k_poshalt<<<dim3(8192), dim3(256), 0, stream>>>(s, xB, pos, ts, 0, p_w, p_b, hp, rem, uw, flag);

  // ---- 6 hops ----
  for (int step = 0; step < 6; step++) {
    gemm_bt<false, true ><<<dim3(64, 12), dim3(256), 0, stream>>>(xB, wqkvB, bqkv, (void*)qkv, 8192, 1536, 512, flag);
    k_vtrans<<<dim3(64, 16), dim3(256), 0, stream>>>(qkv, vt, flag);
    k_attn<<<dim3(64, 8), dim3(512), 0, stream>>>(qkv, vt, attnO, flag);
    gemm_bt512<<<dim3(64, 4, 1), dim3(512), 0, stream>>>(attnO, woB, bo, tmp, nullptr, 8192, 512, 512, 512, flag);
    k_addln1<<<dim3(8192), dim3(256), 0, stream>>>(s, tmp, ln1g, ln1b, x1, x1B, flag);
    gemm_bt<true,  true ><<<dim3(64, 16), dim3(256), 0, stream>>>(x1B, w1B, b1, (void*)hB, 8192, 2048, 512, flag);
    // FFN2 split-K=2: half 0 -> tmp (+bias), half 1 -> s (dead until lnhalt)
    gemm_bt512<<<dim3(64, 4, 2), dim3(512), 0, stream>>>(hB, w2B, b2, tmp, s, 8192, 512, 2048, 1024, flag);
    if (step < 5) {
      k_lnhalt<false><<<dim3(8192), dim3(256), 0, stream>>>(x1, tmp, ln2g, ln2b, pos, ts, step + 1,
                                                            p_w, p_b, s, xB, hp, rem, uw, prev, step, flag);
      k_flag<<<dim3(1), dim3(256), 0, stream>>>(hp, uw, flag);
    } else {
      k_lnhalt<true><<<dim3(8192), dim3(256), 0, stream>>>(x1, tmp, ln2g, ln2b, pos, ts, 0,
                                                           p_w, p_b, s, xB, hp, rem, uw, prev, step, flag);
    }
  }
}

// Round 9
// 690.071 us; speedup vs baseline: 1.1459x; 1.0453x over previous
//
#include <hip/hip_runtime.h>
#include <hip/hip_bf16.h>

typedef __bf16 bf16_t;
typedef __bf16 bf16x8 __attribute__((ext_vector_type(8)));
typedef __bf16 bf16x4 __attribute__((ext_vector_type(4)));
typedef __bf16 bf16x2 __attribute__((ext_vector_type(2)));
typedef float  f32x4  __attribute__((ext_vector_type(4)));
typedef float  f32x2  __attribute__((ext_vector_type(2)));
typedef float  f32x8  __attribute__((ext_vector_type(8)));

static __device__ __forceinline__ void gload_lds16(const void* g, void* l) {
  __builtin_amdgcn_global_load_lds((const __attribute__((address_space(1))) void*)g,
                                   (__attribute__((address_space(3))) void*)l, 16, 0, 0);
}

// LDS chunk swizzle for [rows][32] bf16 tiles: chunk' = chunk ^ ((row>>1)&3).

// ------------------------------------------------------------------
// GEMM  C = A*B^T (+bias, relu opt), bf16 out. 128x128 tile, BK=32,
// 4 waves, 2-phase dbuf. VT=true (QKV): output tiles with n0>=1024
// are the V columns -> written TRANSPOSED into vt (per (b,h): d x key),
// row-major write skipped. Fuses the old k_vtrans away.
// ------------------------------------------------------------------
template <bool RELU, bool VT>
__global__ __launch_bounds__(256)
void gemm_bt(const bf16_t* __restrict__ A, const bf16_t* __restrict__ B,
             const float* __restrict__ bias, bf16_t* __restrict__ C,
             bf16_t* __restrict__ vt, int M, int N, int K,
             const int* __restrict__ flag)
{
  if (*flag) return;
  __shared__ bf16_t As[2][128 * 32];
  __shared__ bf16_t Bs[2][128 * 32];
  const int tid = threadIdx.x;
  const int lane = tid & 63, wave = tid >> 6;
  const int wr = (wave >> 1) * 64, wc = (wave & 1) * 64;
  const int lr = lane & 15, lg = lane >> 4;
  const int m0 = blockIdx.x * 128, n0 = blockIdx.y * 128;

  const bf16_t* Ab = A + (size_t)m0 * K;
  const bf16_t* Bb = B + (size_t)n0 * K;

  f32x4 acc[4][4] = {};

  const int r0 = tid >> 2;
  const int c0 = (((tid & 3) ^ ((r0 >> 1) & 3)) * 8);
  const int lsw = (lg ^ ((lr >> 1) & 3)) * 8;

  auto stage = [&](int buf, int kk) {
    gload_lds16(Ab + (size_t)r0 * K + kk + c0,        &As[buf][tid * 8]);
    gload_lds16(Bb + (size_t)r0 * K + kk + c0,        &Bs[buf][tid * 8]);
    gload_lds16(Ab + (size_t)(r0 + 64) * K + kk + c0, &As[buf][(tid + 256) * 8]);
    gload_lds16(Bb + (size_t)(r0 + 64) * K + kk + c0, &Bs[buf][(tid + 256) * 8]);
  };

  stage(0, 0);
  __syncthreads();

  const int nk = K >> 5;
  for (int t = 0; t < nk; ++t) {
    const int buf = t & 1;
    if (t + 1 < nk) stage(buf ^ 1, (t + 1) * 32);
    bf16x8 af[4], bfr[4];
#pragma unroll
    for (int i = 0; i < 4; i++) af[i]  = *(const bf16x8*)(&As[buf][(wr + i * 16 + lr) * 32 + lsw]);
#pragma unroll
    for (int j = 0; j < 4; j++) bfr[j] = *(const bf16x8*)(&Bs[buf][(wc + j * 16 + lr) * 32 + lsw]);
#pragma unroll
    for (int i = 0; i < 4; i++)
#pragma unroll
      for (int j = 0; j < 4; j++)
        acc[i][j] = __builtin_amdgcn_mfma_f32_16x16x32_bf16(af[i], bfr[j], acc[i][j], 0, 0, 0);
    __syncthreads();
  }

  const int rg = (lane >> 4) * 4;
  if (VT && n0 >= 1024) {
    // V columns: write transposed vt[(b*512 + h*64 + d)][key], 4 keys/store
#pragma unroll
    for (int j = 0; j < 4; j++) {
      const int col = n0 + wc + j * 16 + lr;      // 1024..1535
      const float bv = bias[col];
      const int hd = col - 1024;                  // h*64 + d
#pragma unroll
      for (int i = 0; i < 4; i++) {
        const int row0 = m0 + wr + i * 16 + rg;   // token index
        const int bb = row0 >> 10, key = row0 & 1023;
        bf16x4 q;
#pragma unroll
        for (int r = 0; r < 4; r++) q[r] = (bf16_t)(acc[i][j][r] + bv);
        *(bf16x4*)(vt + ((size_t)bb * 512 + hd) * 1024 + key) = q;
      }
    }
  } else {
#pragma unroll
    for (int j = 0; j < 4; j++) {
      const int col = n0 + wc + j * 16 + lr;
      const float bv = bias ? bias[col] : 0.0f;
#pragma unroll
      for (int i = 0; i < 4; i++) {
#pragma unroll
        for (int r = 0; r < 4; r++) {
          const int row = m0 + wr + i * 16 + rg + r;
          float v = acc[i][j][r] + bv;
          if (RELU) v = fmaxf(v, 0.0f);
          C[(size_t)row * N + col] = (bf16_t)v;
        }
      }
    }
  }
}

// ------------------------------------------------------------------
// GEMM 128x128, 512 threads / 8 waves (2x4), wave = 64x32, 2-phase
// dbuf, bf16 output, optional split-K via gridDim.z (z-half k writes
// buffer Ck; bias folded into half 0 only). O-proj (z=1), FFN2 (z=2).
// ------------------------------------------------------------------
__global__ __launch_bounds__(512)
void gemm_bt512(const bf16_t* __restrict__ A, const bf16_t* __restrict__ B,
                const float* __restrict__ bias, bf16_t* __restrict__ C0,
                bf16_t* __restrict__ C1, int M, int N, int Kfull, int Keff,
                const int* __restrict__ flag)
{
  if (*flag) return;
  __shared__ bf16_t As[2][128 * 32];
  __shared__ bf16_t Bs[2][128 * 32];
  const int tid = threadIdx.x;
  const int lane = tid & 63, wave = tid >> 6;
  const int wr = (wave >> 2) * 64, wc = (wave & 3) * 32;
  const int lr = lane & 15, lg = lane >> 4;
  const int m0 = blockIdx.x * 128, n0 = blockIdx.y * 128;
  const int kb = blockIdx.z;

  const bf16_t* Ab = A + (size_t)m0 * Kfull + (size_t)kb * Keff;
  const bf16_t* Bb = B + (size_t)n0 * Kfull + (size_t)kb * Keff;
  bf16_t* C = kb ? C1 : C0;

  f32x4 acc[4][2] = {};

  const int r0 = tid >> 2;
  const int c0 = (((tid & 3) ^ ((r0 >> 1) & 3)) * 8);
  const int lsw = (lg ^ ((lr >> 1) & 3)) * 8;

  auto stage = [&](int buf, int kk) {
    gload_lds16(Ab + (size_t)r0 * Kfull + kk + c0, &As[buf][tid * 8]);
    gload_lds16(Bb + (size_t)r0 * Kfull + kk + c0, &Bs[buf][tid * 8]);
  };

  stage(0, 0);
  __syncthreads();

  const int nk = Keff >> 5;
  for (int t = 0; t < nk; ++t) {
    const int buf = t & 1;
    if (t + 1 < nk) stage(buf ^ 1, (t + 1) * 32);
    bf16x8 af[4], bfr[2];
#pragma unroll
    for (int i = 0; i < 4; i++) af[i]  = *(const bf16x8*)(&As[buf][(wr + i * 16 + lr) * 32 + lsw]);
#pragma unroll
    for (int j = 0; j < 2; j++) bfr[j] = *(const bf16x8*)(&Bs[buf][(wc + j * 16 + lr) * 32 + lsw]);
#pragma unroll
    for (int i = 0; i < 4; i++)
#pragma unroll
      for (int j = 0; j < 2; j++)
        acc[i][j] = __builtin_amdgcn_mfma_f32_16x16x32_bf16(af[i], bfr[j], acc[i][j], 0, 0, 0);
    __syncthreads();
  }

  const int rg = (lane >> 4) * 4;
#pragma unroll
  for (int j = 0; j < 2; j++) {
    const int col = n0 + wc + j * 16 + lr;
    const float bv = (bias && kb == 0) ? bias[col] : 0.0f;
#pragma unroll
    for (int i = 0; i < 4; i++) {
#pragma unroll
      for (int r = 0; r < 4; r++) {
        const int row = m0 + wr + i * 16 + rg + r;
        C[(size_t)row * N + col] = (bf16_t)(acc[i][j][r] + bv);
      }
    }
  }
}

// ------------------------------------------------------------------
// Flash attention (swapped QK^T): S^T = mfma(K,Q), per-lane scalar
// online softmax with defer-max, cvt_pk P-packing, K/V^T LDS dbuf
// with XOR swizzle, setprio around MFMA.
// ------------------------------------------------------------------
__global__ __launch_bounds__(512)
void k_attn(const bf16_t* __restrict__ qkv, const bf16_t* __restrict__ vt,
            bf16_t* __restrict__ out, const int* __restrict__ flag)
{
  if (*flag) return;
  const int bh = blockIdx.x;
  const int qt = blockIdx.y;
  const int b = bh >> 3, h = bh & 7;
  const int tid = threadIdx.x, lane = tid & 63, wave = tid >> 6;
  const int lr = lane & 15, lg = lane >> 4;

  __shared__ bf16_t Ks[2][4096];
  __shared__ bf16_t Vs[2][4096];
  __shared__ bf16_t Pl[8][16][68];

  const size_t RS = 1536;
  const bf16_t* Qb = qkv + ((size_t)(b * 1024 + qt * 128)) * RS + h * 64;
  const bf16_t* Kb = qkv + ((size_t)(b * 1024)) * RS + 512 + h * 64;
  const bf16_t* Vt = vt + (size_t)bh * 64 * 1024;

  const float SC = 0.125f * 1.4426950408889634f;
  bf16x8 qf[2];
#pragma unroll
  for (int ks = 0; ks < 2; ks++) {
    bf16x8 q = *(const bf16x8*)(Qb + (size_t)(wave * 16 + lr) * RS + lg * 8 + ks * 32);
#pragma unroll
    for (int u = 0; u < 8; u++) q[u] = (bf16_t)((float)q[u] * SC);
    qf[ks] = q;
  }

  f32x4 o[4] = {};
  float m_ = -1e30f, ls_ = 0.0f;     // per-lane: q-row = wave*16 + lane&15

  auto stage = [&](int buf, int kv) {
    const int c = tid;
    const int r = c >> 3;
    const int ce = (c & 7) * 8;
    const int cs = ce ^ ((r & 7) << 3);
    gload_lds16(Kb + (size_t)(kv * 64 + r) * RS + cs, &Ks[buf][c * 8]);
    gload_lds16(Vt + (size_t)r * 1024 + kv * 64 + cs, &Vs[buf][c * 8]);
  };

  stage(0, 0);
  __syncthreads();

  const int sw = (lr & 7) << 3;

  for (int kv = 0; kv < 16; kv++) {
    const int buf = kv & 1;
    if (kv < 15) stage(buf ^ 1, kv + 1);

    f32x4 sfr[4];
    __builtin_amdgcn_s_setprio(1);
#pragma unroll
    for (int j = 0; j < 4; j++) {
      f32x4 z = {};
#pragma unroll
      for (int ks = 0; ks < 2; ks++) {
        bf16x8 kf = *(const bf16x8*)(&Ks[buf][(j * 16 + lr) * 64 + ((lg * 8 + ks * 32) ^ sw)]);
        z = __builtin_amdgcn_mfma_f32_16x16x32_bf16(kf, qf[ks], z, 0, 0, 0);
      }
      sfr[j] = z;
    }
    __builtin_amdgcn_s_setprio(0);

    float px = sfr[0][0];
#pragma unroll
    for (int j = 0; j < 4; j++)
#pragma unroll
      for (int r = 0; r < 4; r++) px = fmaxf(px, sfr[j][r]);
    if (!__all(px <= m_ + 8.0f)) {
      float mx = fmaxf(px, __shfl_xor(px, 16, 64));
      mx = fmaxf(mx, __shfl_xor(mx, 32, 64));
      mx = fmaxf(mx, m_);
      const float al = __builtin_amdgcn_exp2f(m_ - mx);
      m_ = mx;
      ls_ *= al;
      float aq[4];
#pragma unroll
      for (int r = 0; r < 4; r++) aq[r] = __shfl(al, lg * 4 + r, 64);
#pragma unroll
      for (int j = 0; j < 4; j++)
#pragma unroll
        for (int r = 0; r < 4; r++) o[j][r] *= aq[r];
    }

    float ps = 0.0f;
#pragma unroll
    for (int j = 0; j < 4; j++) {
      const float p0 = __builtin_amdgcn_exp2f(sfr[j][0] - m_);
      const float p1 = __builtin_amdgcn_exp2f(sfr[j][1] - m_);
      const float p2 = __builtin_amdgcn_exp2f(sfr[j][2] - m_);
      const float p3 = __builtin_amdgcn_exp2f(sfr[j][3] - m_);
      ps += (p0 + p1) + (p2 + p3);
      unsigned lo, hi;
      asm("v_cvt_pk_bf16_f32 %0, %1, %2" : "=v"(lo) : "v"(p0), "v"(p1));
      asm("v_cvt_pk_bf16_f32 %0, %1, %2" : "=v"(hi) : "v"(p2), "v"(p3));
      uint2 w; w.x = lo; w.y = hi;
      *(uint2*)(&Pl[wave][lr][j * 16 + lg * 4]) = w;
    }
    ls_ += ps;

    __builtin_amdgcn_s_setprio(1);
#pragma unroll
    for (int ks = 0; ks < 2; ks++) {
      bf16x8 pa = *(const bf16x8*)(&Pl[wave][lr][lg * 8 + ks * 32]);
#pragma unroll
      for (int j = 0; j < 4; j++) {
        bf16x8 vb = *(const bf16x8*)(&Vs[buf][(j * 16 + lr) * 64 + ((lg * 8 + ks * 32) ^ sw)]);
        o[j] = __builtin_amdgcn_mfma_f32_16x16x32_bf16(pa, vb, o[j], 0, 0, 0);
      }
    }
    __builtin_amdgcn_s_setprio(0);

    __syncthreads();
  }

  ls_ += __shfl_xor(ls_, 16, 64);
  ls_ += __shfl_xor(ls_, 32, 64);
  float lsq[4];
#pragma unroll
  for (int r = 0; r < 4; r++) lsq[r] = __shfl(ls_, lg * 4 + r, 64);

  const size_t orow = (size_t)(b * 1024 + qt * 128 + wave * 16 + lg * 4);
#pragma unroll
  for (int j = 0; j < 4; j++)
#pragma unroll
    for (int r = 0; r < 4; r++)
      out[(orow + r) * 512 + h * 64 + j * 16 + lr] = (bf16_t)(o[j][r] / lsq[r]);
}

// ------------------------------------------------------------------
// s += pos + ts[0]; p = sigmoid(s . p_w + p_b); ACT halting update.
// Step-0 only (later steps fused into k_lnhalt).
// ------------------------------------------------------------------
__global__ __launch_bounds__(256)
void k_poshalt(float* __restrict__ s, bf16_t* __restrict__ xbf,
               const float* __restrict__ pos, const float* __restrict__ ts, int step,
               const float* __restrict__ pw, const float* __restrict__ pb,
               float* __restrict__ hp, float* __restrict__ rem, float* __restrict__ uw,
               const int* __restrict__ flag)
{
  if (*flag) return;
  const int row = blockIdx.x;
  const int l = row & 1023;
  const int t = threadIdx.x;
  const size_t base = (size_t)row * 512;
  float v0 = s[base + t]       + pos[l * 512 + t]       + ts[step * 512 + t];
  float v1 = s[base + 256 + t] + pos[l * 512 + 256 + t] + ts[step * 512 + 256 + t];
  s[base + t] = v0; s[base + 256 + t] = v1;
  xbf[base + t] = (bf16_t)v0; xbf[base + 256 + t] = (bf16_t)v1;

  float d = v0 * pw[t] + v1 * pw[256 + t];
#pragma unroll
  for (int mk = 1; mk < 64; mk <<= 1) d += __shfl_xor(d, mk, 64);
  __shared__ float part[4];
  if ((t & 63) == 0) part[t >> 6] = d;
  __syncthreads();
  if (t == 0) {
    const float z = part[0] + part[1] + part[2] + part[3] + pb[0];
    const float p = 1.0f / (1.0f + expf(-z));
    float h = 0.0f, rm = 0.0f;
    const float still0 = 1.0f;
    const float cond = h + p * still0;
    const float nh = (cond > 0.9f) ? still0 : 0.0f;
    const float st = (cond <= 0.9f) ? still0 : 0.0f;
    h += p * st;
    rm += nh * (1.0f - h);
    h += nh * rm;
    hp[row] = h; rem[row] = rm;
    uw[row] = p * st + nh * rm;
  }
}

// ------------------------------------------------------------------
// Post-attn LN: y = LayerNorm(s + oproj_bf16); write y bf16 only.
// ------------------------------------------------------------------
__global__ __launch_bounds__(256)
void k_addln1(const float* __restrict__ sIn, const bf16_t* __restrict__ ob,
              const float* __restrict__ g, const float* __restrict__ be,
              bf16_t* __restrict__ ybf, const int* __restrict__ flag)
{
  if (*flag) return;
  const int row = blockIdx.x, t = threadIdx.x;
  const size_t base = (size_t)row * 512 + 2 * t;
  f32x2 sv = *(const f32x2*)(sIn + base);
  bf16x2 ov = *(const bf16x2*)(ob + base);
  const float v0 = sv[0] + (float)ov[0];
  const float v1 = sv[1] + (float)ov[1];
  float s1 = v0 + v1, s2 = v0 * v0 + v1 * v1;
#pragma unroll
  for (int mk = 1; mk < 64; mk <<= 1) { s1 += __shfl_xor(s1, mk, 64); s2 += __shfl_xor(s2, mk, 64); }
  __shared__ float p1[4], p2[4];
  if ((t & 63) == 0) { p1[t >> 6] = s1; p2[t >> 6] = s2; }
  __syncthreads();
  s1 = p1[0] + p1[1] + p1[2] + p1[3];
  s2 = p2[0] + p2[1] + p2[2] + p2[3];
  const float mean = s1 * (1.0f / 512.0f);
  const float var  = s2 * (1.0f / 512.0f) - mean * mean;
  const float ri = rsqrtf(var + 1e-5f);
  f32x2 gv = *(const f32x2*)(g + 2 * t);
  f32x2 bv = *(const f32x2*)(be + 2 * t);
  bf16x2 yo;
  yo[0] = (bf16_t)((v0 - mean) * ri * gv[0] + bv[0]);
  yo[1] = (bf16_t)((v1 - mean) * ri * gv[1] + bv[1]);
  *(bf16x2*)(ybf + base) = yo;
}

// ------------------------------------------------------------------
// Fused bottom-of-step: y = LN(x1B + pA + pB) (bf16 inputs);
// prev = y*uw + prev*(1-uw); then NEXT step's pos/ts add + halting.
// ------------------------------------------------------------------
template <bool LAST>
__global__ __launch_bounds__(256)
void k_lnhalt(const bf16_t* __restrict__ x1b, const bf16_t* __restrict__ pA,
              const bf16_t* __restrict__ pB,
              const float* __restrict__ g, const float* __restrict__ be,
              const float* __restrict__ pos, const float* __restrict__ ts, int nstep,
              const float* __restrict__ pw, const float* __restrict__ pb,
              float* __restrict__ s, bf16_t* __restrict__ xbf,
              float* __restrict__ hp, float* __restrict__ rem, float* __restrict__ uw,
              float* __restrict__ prev, int step, const int* __restrict__ flag)
{
  if (*flag) return;
  const int row = blockIdx.x, t = threadIdx.x;
  const int l = row & 1023;
  const size_t base = (size_t)row * 512 + 2 * t;
  bf16x2 xv = *(const bf16x2*)(x1b + base);
  bf16x2 av = *(const bf16x2*)(pA + base);
  bf16x2 bv2 = *(const bf16x2*)(pB + base);
  const float a0 = (float)xv[0] + (float)av[0] + (float)bv2[0];
  const float a1 = (float)xv[1] + (float)av[1] + (float)bv2[1];
  float s1 = a0 + a1, s2 = a0 * a0 + a1 * a1;
#pragma unroll
  for (int mk = 1; mk < 64; mk <<= 1) { s1 += __shfl_xor(s1, mk, 64); s2 += __shfl_xor(s2, mk, 64); }
  __shared__ float p1[4], p2[4], pd[4];
  if ((t & 63) == 0) { p1[t >> 6] = s1; p2[t >> 6] = s2; }
  __syncthreads();
  s1 = p1[0] + p1[1] + p1[2] + p1[3];
  s2 = p2[0] + p2[1] + p2[2] + p2[3];
  const float mean = s1 * (1.0f / 512.0f);
  const float var  = s2 * (1.0f / 512.0f) - mean * mean;
  const float ri = rsqrtf(var + 1e-5f);
  f32x2 gv = *(const f32x2*)(g + 2 * t);
  f32x2 bev = *(const f32x2*)(be + 2 * t);
  const float y0 = (a0 - mean) * ri * gv[0] + bev[0];
  const float y1 = (a1 - mean) * ri * gv[1] + bev[1];

  const float w = uw[row];
  if (step == 0) {
    f32x2 np; np[0] = y0 * w; np[1] = y1 * w;
    *(f32x2*)(prev + base) = np;
  } else if (w != 0.0f) {
    f32x2 pv = *(const f32x2*)(prev + base);
    f32x2 np;
    np[0] = y0 * w + pv[0] * (1.0f - w);
    np[1] = y1 * w + pv[1] * (1.0f - w);
    *(f32x2*)(prev + base) = np;
  }

  if (LAST) return;

  f32x2 pp = *(const f32x2*)(pos + l * 512 + 2 * t);
  f32x2 tv = *(const f32x2*)(ts + nstep * 512 + 2 * t);
  const float v0 = y0 + pp[0] + tv[0];
  const float v1 = y1 + pp[1] + tv[1];
  f32x2 sv; sv[0] = v0; sv[1] = v1;
  *(f32x2*)(s + base) = sv;
  bf16x2 xo; xo[0] = (bf16_t)v0; xo[1] = (bf16_t)v1;
  *(bf16x2*)(xbf + base) = xo;

  f32x2 wv = *(const f32x2*)(pw + 2 * t);
  float d = v0 * wv[0] + v1 * wv[1];
#pragma unroll
  for (int mk = 1; mk < 64; mk <<= 1) d += __shfl_xor(d, mk, 64);
  if ((t & 63) == 0) pd[t >> 6] = d;
  __syncthreads();
  if (t == 0) {
    const float z = pd[0] + pd[1] + pd[2] + pd[3] + pb[0];
    const float p = 1.0f / (1.0f + expf(-z));
    float h  = hp[row];
    float rm = rem[row];
    const float still0 = (h < 1.0f) ? 1.0f : 0.0f;
    const float cond = h + p * still0;
    const float nh = (cond > 0.9f) ? still0 : 0.0f;
    const float st = (cond <= 0.9f) ? still0 : 0.0f;
    h += p * st;
    rm += nh * (1.0f - h);
    h += nh * rm;
    hp[row] = h; rem[row] = rm;
    uw[row] = p * st + nh * rm;
  }
}

// ------------------------------------------------------------------
// All-halted detector: flag=1 once min(hp) >= 1 AND max(uw) == 0.
// ------------------------------------------------------------------
__global__ __launch_bounds__(256)
void k_flag(const float* __restrict__ hp, const float* __restrict__ uw,
            int* __restrict__ flag)
{
  if (*flag) return;
  const int t = threadIdx.x;
  float mn = 1e30f, mxw = 0.0f;
#pragma unroll
  for (int i = 0; i < 4; i++) {
    f32x8 v = *(const f32x8*)(hp + (t + i * 256) * 8);
    f32x8 u = *(const f32x8*)(uw + (t + i * 256) * 8);
#pragma unroll
    for (int q = 0; q < 8; q++) { mn = fminf(mn, v[q]); mxw = fmaxf(mxw, u[q]); }
  }
#pragma unroll
  for (int mk = 1; mk < 64; mk <<= 1) {
    mn = fminf(mn, __shfl_xor(mn, mk, 64));
    mxw = fmaxf(mxw, __shfl_xor(mxw, mk, 64));
  }
  __shared__ float part[4], partw[4];
  if ((t & 63) == 0) { part[t >> 6] = mn; partw[t >> 6] = mxw; }
  __syncthreads();
  if (t == 0) {
    mn = fminf(fminf(part[0], part[1]), fminf(part[2], part[3]));
    mxw = fmaxf(fmaxf(partw[0], partw[1]), fmaxf(partw[2], partw[3]));
    if (mn >= 1.0f && mxw == 0.0f) *flag = 1;
  }
}

__global__ void k_zeroflag(int* __restrict__ flag) { *flag = 0; }

// ------------------------------------------------------------------
__global__ void k_pos_ts(float* __restrict__ pos, float* __restrict__ ts,
                         const int* __restrict__ outer)
{
  const int idx = blockIdx.x * 256 + threadIdx.x;
  const int l = idx >> 9, i = idx & 511;
  const float dt = expf((float)(i & ~1) * (-9.210340371976184f / 512.0f));
  const float a = (float)l * dt;
  pos[idx] = (i & 1) ? cosf(a) : sinf(a);
  if (l < 6) {
    const int gidx = 6 * outer[0] + l;
    const float a2 = (float)gidx * dt;
    ts[l * 512 + i] = (i & 1) ? cosf(a2) : sinf(a2);
  }
}

__global__ void k_f2b(const float* __restrict__ in, bf16_t* __restrict__ out, int n)
{
  const int i = blockIdx.x * 256 + threadIdx.x;
  if (i < n) out[i] = (bf16_t)in[i];
}

__global__ void k_copy(const float* __restrict__ in, float* __restrict__ out, int n)
{
  const int i = blockIdx.x * 256 + threadIdx.x;
  if (i < n) out[i] = in[i];
}

// ------------------------------------------------------------------
extern "C" void kernel_launch(void* const* d_in, const int* in_sizes, int n_in,
                              void* d_out, int out_size, void* d_ws, size_t ws_size,
                              hipStream_t stream)
{
  const float* state = (const float*)d_in[0];
  const int*   outer = (const int*)d_in[1];
  const float* p_w   = (const float*)d_in[2];
  const float* p_b   = (const float*)d_in[3];
  const float* wq = (const float*)d_in[4];
  const float* bq = (const float*)d_in[5];
  const float* wk = (const float*)d_in[6];
  const float* bk = (const float*)d_in[7];
  const float* wv = (const float*)d_in[8];
  const float* bv = (const float*)d_in[9];
  const float* wo = (const float*)d_in[10];
  const float* bo = (const float*)d_in[11];
  const float* w1 = (const float*)d_in[12];
  const float* b1 = (const float*)d_in[13];
  const float* w2 = (const float*)d_in[14];
  const float* b2 = (const float*)d_in[15];
  const float* ln1g = (const float*)d_in[16];
  const float* ln1b = (const float*)d_in[17];
  const float* ln2g = (const float*)d_in[18];
  const float* ln2b = (const float*)d_in[19];
  float* prev = (float*)d_out;

  char* cur = (char*)d_ws;
  auto take = [&](size_t n) { char* p = cur; cur += (n + 255) & ~(size_t)255; return p; };
  float*  pos   = (float*) take((size_t)1024 * 512 * 4);
  float*  ts    = (float*) take(6 * 512 * 4);
  bf16_t* wqkvB = (bf16_t*)take((size_t)1536 * 512 * 2);
  bf16_t* woB   = (bf16_t*)take((size_t)512 * 512 * 2);
  bf16_t* w1B   = (bf16_t*)take((size_t)2048 * 512 * 2);
  bf16_t* w2B   = (bf16_t*)take((size_t)512 * 2048 * 2);
  float*  bqkv  = (float*) take(1536 * 4);
  float*  s     = (float*) take((size_t)8192 * 512 * 4);  // fp32 state
  bf16_t* x1B   = (bf16_t*)take((size_t)8192 * 512 * 2);  // LN1 output (residual + FFN1 input)
  bf16_t* pA    = (bf16_t*)take((size_t)8192 * 512 * 2);  // FFN2 split-K half0 (+bias)
  char*   tmp   = take((size_t)8192 * 512 * 2);           // vt during QKV+attn, then O-proj out
  bf16_t* attnO = (bf16_t*)take((size_t)8192 * 512 * 2);  // attn out, then FFN2 half1 (pB)
  float*  hp    = (float*) take(8192 * 4);
  float*  rem   = (float*) take(8192 * 4);
  float*  uw    = (float*) take(8192 * 4);
  int*    flag  = (int*)   take(4);
  char*   region = take((size_t)8192 * 2048 * 2);
  bf16_t* xB  = (bf16_t*)region;                            // bf16 state (QKV input)
  bf16_t* qkv = (bf16_t*)(region + (size_t)8192 * 512 * 2); // Q|K cols live, V garbage
  bf16_t* hB  = (bf16_t*)region;                            // FFN1 out (overwrites xB+qkv)
  bf16_t* vt  = (bf16_t*)tmp;                               // V^T, written by QKV epilogue
  bf16_t* obf = (bf16_t*)tmp;                               // O-proj out (after attn)
  bf16_t* pB  = attnO;                                      // FFN2 half1 (after O-proj)

  // ---- precompute ----
  k_zeroflag<<<dim3(1), dim3(1), 0, stream>>>(flag);
  k_pos_ts<<<dim3(2048), dim3(256), 0, stream>>>(pos, ts, outer);
  k_f2b<<<dim3(1024), dim3(256), 0, stream>>>(wq, wqkvB,               512 * 512);
  k_f2b<<<dim3(1024), dim3(256), 0, stream>>>(wk, wqkvB + 512 * 512,   512 * 512);
  k_f2b<<<dim3(1024), dim3(256), 0, stream>>>(wv, wqkvB + 1024 * 512,  512 * 512);
  k_f2b<<<dim3(1024), dim3(256), 0, stream>>>(wo, woB,                 512 * 512);
  k_f2b<<<dim3(4096), dim3(256), 0, stream>>>(w1, w1B,                 2048 * 512);
  k_f2b<<<dim3(4096), dim3(256), 0, stream>>>(w2, w2B,                 512 * 2048);
  k_copy<<<dim3(2), dim3(256), 0, stream>>>(bq, bqkv,        512);
  k_copy<<<dim3(2), dim3(256), 0, stream>>>(bk, bqkv + 512,  512);
  k_copy<<<dim3(2), dim3(256), 0, stream>>>(bv, bqkv + 1024, 512);
  k_copy<<<dim3(16384), dim3(256), 0, stream>>>(state, s, 8192 * 512);

  // step 0 top: pos/ts add + halting gate
  k_poshalt<<<dim3(8192), dim3(256), 0, stream>>>(s, xB, pos, ts, 0, p_w, p_b, hp, rem, uw, flag);

  // ---- 6 hops ----
  for (int step = 0; step < 6; step++) {
    gemm_bt<false, true ><<<dim3(64, 12), dim3(256), 0, stream>>>(xB, wqkvB, bqkv, qkv, vt, 8192, 1536, 512, flag);
    k_attn<<<dim3(64, 8), dim3(512), 0, stream>>>(qkv, vt, attnO, flag);
    gemm_bt512<<<dim3(64, 4, 1), dim3(512), 0, stream>>>(attnO, woB, bo, obf, nullptr, 8192, 512, 512, 512, flag);
    k_addln1<<<dim3(8192), dim3(256), 0, stream>>>(s, obf, ln1g, ln1b, x1B, flag);
    gemm_bt<true, false><<<dim3(64, 16), dim3(256), 0, stream>>>(x1B, w1B, b1, hB, nullptr, 8192, 2048, 512, flag);
    gemm_bt512<<<dim3(64, 4, 2), dim3(512), 0, stream>>>(hB, w2B, b2, pA, pB, 8192, 512, 2048, 1024, flag);
    if (step < 5) {
      k_lnhalt<false><<<dim3(8192), dim3(256), 0, stream>>>(x1B, pA, pB, ln2g, ln2b, pos, ts, step + 1,
                                                            p_w, p_b, s, xB, hp, rem, uw, prev, step, flag);
      k_flag<<<dim3(1), dim3(256), 0, stream>>>(hp, uw, flag);
    } else {
      k_lnhalt<true><<<dim3(8192), dim3(256), 0, stream>>>(x1B, pA, pB, ln2g, ln2b, pos, ts, 0,
                                                           p_w, p_b, s, xB, hp, rem, uw, prev, step, flag);
    }
  }
}

// Round 10
// 653.261 us; speedup vs baseline: 1.2104x; 1.0563x over previous
//
#include <hip/hip_runtime.h>
#include <hip/hip_bf16.h>

typedef __bf16 bf16_t;
typedef __bf16 bf16x8 __attribute__((ext_vector_type(8)));
typedef __bf16 bf16x4 __attribute__((ext_vector_type(4)));
typedef __bf16 bf16x2 __attribute__((ext_vector_type(2)));
typedef float  f32x4  __attribute__((ext_vector_type(4)));
typedef float  f32x2  __attribute__((ext_vector_type(2)));
typedef float  f32x8  __attribute__((ext_vector_type(8)));

static __device__ __forceinline__ void gload_lds16(const void* g, void* l) {
  __builtin_amdgcn_global_load_lds((const __attribute__((address_space(1))) void*)g,
                                   (__attribute__((address_space(3))) void*)l, 16, 0, 0);
}

// LDS chunk swizzle for [rows][32] bf16 tiles: chunk' = chunk ^ ((row>>1)&3).
// Per-batch dead flags: bflag[b]==1 once all 1024 positions of batch b have
// halted (hp>=1) AND uw==0 -> that batch's remaining compute is provably
// dead w.r.t. prev (attention never mixes across batches). Bit-exact skip.

// ------------------------------------------------------------------
// GEMM  C = A*B^T (+bias, relu opt), bf16 out. 128x128 tile, BK=32,
// 4 waves, 2-phase dbuf. VT=true (QKV): output tiles with n0>=1024
// are the V columns -> written TRANSPOSED into vt (per (b,h): d x key).
// M-tiles (128 rows) align with batches (1024 rows): batch = bid.x>>3.
// ------------------------------------------------------------------
template <bool RELU, bool VT>
__global__ __launch_bounds__(256)
void gemm_bt(const bf16_t* __restrict__ A, const bf16_t* __restrict__ B,
             const float* __restrict__ bias, bf16_t* __restrict__ C,
             bf16_t* __restrict__ vt, int M, int N, int K,
             const int* __restrict__ bflag)
{
  if (bflag[blockIdx.x >> 3]) return;
  __shared__ bf16_t As[2][128 * 32];
  __shared__ bf16_t Bs[2][128 * 32];
  const int tid = threadIdx.x;
  const int lane = tid & 63, wave = tid >> 6;
  const int wr = (wave >> 1) * 64, wc = (wave & 1) * 64;
  const int lr = lane & 15, lg = lane >> 4;
  const int m0 = blockIdx.x * 128, n0 = blockIdx.y * 128;

  const bf16_t* Ab = A + (size_t)m0 * K;
  const bf16_t* Bb = B + (size_t)n0 * K;

  f32x4 acc[4][4] = {};

  const int r0 = tid >> 2;
  const int c0 = (((tid & 3) ^ ((r0 >> 1) & 3)) * 8);
  const int lsw = (lg ^ ((lr >> 1) & 3)) * 8;

  auto stage = [&](int buf, int kk) {
    gload_lds16(Ab + (size_t)r0 * K + kk + c0,        &As[buf][tid * 8]);
    gload_lds16(Bb + (size_t)r0 * K + kk + c0,        &Bs[buf][tid * 8]);
    gload_lds16(Ab + (size_t)(r0 + 64) * K + kk + c0, &As[buf][(tid + 256) * 8]);
    gload_lds16(Bb + (size_t)(r0 + 64) * K + kk + c0, &Bs[buf][(tid + 256) * 8]);
  };

  stage(0, 0);
  __syncthreads();

  const int nk = K >> 5;
  for (int t = 0; t < nk; ++t) {
    const int buf = t & 1;
    if (t + 1 < nk) stage(buf ^ 1, (t + 1) * 32);
    bf16x8 af[4], bfr[4];
#pragma unroll
    for (int i = 0; i < 4; i++) af[i]  = *(const bf16x8*)(&As[buf][(wr + i * 16 + lr) * 32 + lsw]);
#pragma unroll
    for (int j = 0; j < 4; j++) bfr[j] = *(const bf16x8*)(&Bs[buf][(wc + j * 16 + lr) * 32 + lsw]);
#pragma unroll
    for (int i = 0; i < 4; i++)
#pragma unroll
      for (int j = 0; j < 4; j++)
        acc[i][j] = __builtin_amdgcn_mfma_f32_16x16x32_bf16(af[i], bfr[j], acc[i][j], 0, 0, 0);
    __syncthreads();
  }

  const int rg = (lane >> 4) * 4;
  if (VT && n0 >= 1024) {
#pragma unroll
    for (int j = 0; j < 4; j++) {
      const int col = n0 + wc + j * 16 + lr;      // 1024..1535
      const float bv = bias[col];
      const int hd = col - 1024;                  // h*64 + d
#pragma unroll
      for (int i = 0; i < 4; i++) {
        const int row0 = m0 + wr + i * 16 + rg;   // token index
        const int bb = row0 >> 10, key = row0 & 1023;
        bf16x4 q;
#pragma unroll
        for (int r = 0; r < 4; r++) q[r] = (bf16_t)(acc[i][j][r] + bv);
        *(bf16x4*)(vt + ((size_t)bb * 512 + hd) * 1024 + key) = q;
      }
    }
  } else {
#pragma unroll
    for (int j = 0; j < 4; j++) {
      const int col = n0 + wc + j * 16 + lr;
      const float bv = bias ? bias[col] : 0.0f;
#pragma unroll
      for (int i = 0; i < 4; i++) {
#pragma unroll
        for (int r = 0; r < 4; r++) {
          const int row = m0 + wr + i * 16 + rg + r;
          float v = acc[i][j][r] + bv;
          if (RELU) v = fmaxf(v, 0.0f);
          C[(size_t)row * N + col] = (bf16_t)v;
        }
      }
    }
  }
}

// ------------------------------------------------------------------
// GEMM 128x128, 512 threads / 8 waves (2x4), wave = 64x32, 2-phase
// dbuf, bf16 output, optional split-K via gridDim.z.
// ------------------------------------------------------------------
__global__ __launch_bounds__(512)
void gemm_bt512(const bf16_t* __restrict__ A, const bf16_t* __restrict__ B,
                const float* __restrict__ bias, bf16_t* __restrict__ C0,
                bf16_t* __restrict__ C1, int M, int N, int Kfull, int Keff,
                const int* __restrict__ bflag)
{
  if (bflag[blockIdx.x >> 3]) return;
  __shared__ bf16_t As[2][128 * 32];
  __shared__ bf16_t Bs[2][128 * 32];
  const int tid = threadIdx.x;
  const int lane = tid & 63, wave = tid >> 6;
  const int wr = (wave >> 2) * 64, wc = (wave & 3) * 32;
  const int lr = lane & 15, lg = lane >> 4;
  const int m0 = blockIdx.x * 128, n0 = blockIdx.y * 128;
  const int kb = blockIdx.z;

  const bf16_t* Ab = A + (size_t)m0 * Kfull + (size_t)kb * Keff;
  const bf16_t* Bb = B + (size_t)n0 * Kfull + (size_t)kb * Keff;
  bf16_t* C = kb ? C1 : C0;

  f32x4 acc[4][2] = {};

  const int r0 = tid >> 2;
  const int c0 = (((tid & 3) ^ ((r0 >> 1) & 3)) * 8);
  const int lsw = (lg ^ ((lr >> 1) & 3)) * 8;

  auto stage = [&](int buf, int kk) {
    gload_lds16(Ab + (size_t)r0 * Kfull + kk + c0, &As[buf][tid * 8]);
    gload_lds16(Bb + (size_t)r0 * Kfull + kk + c0, &Bs[buf][tid * 8]);
  };

  stage(0, 0);
  __syncthreads();

  const int nk = Keff >> 5;
  for (int t = 0; t < nk; ++t) {
    const int buf = t & 1;
    if (t + 1 < nk) stage(buf ^ 1, (t + 1) * 32);
    bf16x8 af[4], bfr[2];
#pragma unroll
    for (int i = 0; i < 4; i++) af[i]  = *(const bf16x8*)(&As[buf][(wr + i * 16 + lr) * 32 + lsw]);
#pragma unroll
    for (int j = 0; j < 2; j++) bfr[j] = *(const bf16x8*)(&Bs[buf][(wc + j * 16 + lr) * 32 + lsw]);
#pragma unroll
    for (int i = 0; i < 4; i++)
#pragma unroll
      for (int j = 0; j < 2; j++)
        acc[i][j] = __builtin_amdgcn_mfma_f32_16x16x32_bf16(af[i], bfr[j], acc[i][j], 0, 0, 0);
    __syncthreads();
  }

  const int rg = (lane >> 4) * 4;
#pragma unroll
  for (int j = 0; j < 2; j++) {
    const int col = n0 + wc + j * 16 + lr;
    const float bv = (bias && kb == 0) ? bias[col] : 0.0f;
#pragma unroll
    for (int i = 0; i < 4; i++) {
#pragma unroll
      for (int r = 0; r < 4; r++) {
        const int row = m0 + wr + i * 16 + rg + r;
        C[(size_t)row * N + col] = (bf16_t)(acc[i][j][r] + bv);
      }
    }
  }
}

// ------------------------------------------------------------------
// Flash attention (swapped QK^T): S^T = mfma(K,Q), per-lane scalar
// online softmax with defer-max, cvt_pk P-packing, K/V^T LDS dbuf
// with XOR swizzle, setprio around MFMA.
// ------------------------------------------------------------------
__global__ __launch_bounds__(512)
void k_attn(const bf16_t* __restrict__ qkv, const bf16_t* __restrict__ vt,
            bf16_t* __restrict__ out, const int* __restrict__ bflag)
{
  if (bflag[blockIdx.x >> 3]) return;
  const int bh = blockIdx.x;
  const int qt = blockIdx.y;
  const int b = bh >> 3, h = bh & 7;
  const int tid = threadIdx.x, lane = tid & 63, wave = tid >> 6;
  const int lr = lane & 15, lg = lane >> 4;

  __shared__ bf16_t Ks[2][4096];
  __shared__ bf16_t Vs[2][4096];
  __shared__ bf16_t Pl[8][16][68];

  const size_t RS = 1536;
  const bf16_t* Qb = qkv + ((size_t)(b * 1024 + qt * 128)) * RS + h * 64;
  const bf16_t* Kb = qkv + ((size_t)(b * 1024)) * RS + 512 + h * 64;
  const bf16_t* Vt = vt + (size_t)bh * 64 * 1024;

  const float SC = 0.125f * 1.4426950408889634f;
  bf16x8 qf[2];
#pragma unroll
  for (int ks = 0; ks < 2; ks++) {
    bf16x8 q = *(const bf16x8*)(Qb + (size_t)(wave * 16 + lr) * RS + lg * 8 + ks * 32);
#pragma unroll
    for (int u = 0; u < 8; u++) q[u] = (bf16_t)((float)q[u] * SC);
    qf[ks] = q;
  }

  f32x4 o[4] = {};
  float m_ = -1e30f, ls_ = 0.0f;     // per-lane: q-row = wave*16 + lane&15

  auto stage = [&](int buf, int kv) {
    const int c = tid;
    const int r = c >> 3;
    const int ce = (c & 7) * 8;
    const int cs = ce ^ ((r & 7) << 3);
    gload_lds16(Kb + (size_t)(kv * 64 + r) * RS + cs, &Ks[buf][c * 8]);
    gload_lds16(Vt + (size_t)r * 1024 + kv * 64 + cs, &Vs[buf][c * 8]);
  };

  stage(0, 0);
  __syncthreads();

  const int sw = (lr & 7) << 3;

  for (int kv = 0; kv < 16; kv++) {
    const int buf = kv & 1;
    if (kv < 15) stage(buf ^ 1, kv + 1);

    f32x4 sfr[4];
    __builtin_amdgcn_s_setprio(1);
#pragma unroll
    for (int j = 0; j < 4; j++) {
      f32x4 z = {};
#pragma unroll
      for (int ks = 0; ks < 2; ks++) {
        bf16x8 kf = *(const bf16x8*)(&Ks[buf][(j * 16 + lr) * 64 + ((lg * 8 + ks * 32) ^ sw)]);
        z = __builtin_amdgcn_mfma_f32_16x16x32_bf16(kf, qf[ks], z, 0, 0, 0);
      }
      sfr[j] = z;
    }
    __builtin_amdgcn_s_setprio(0);

    float px = sfr[0][0];
#pragma unroll
    for (int j = 0; j < 4; j++)
#pragma unroll
      for (int r = 0; r < 4; r++) px = fmaxf(px, sfr[j][r]);
    if (!__all(px <= m_ + 8.0f)) {
      float mx = fmaxf(px, __shfl_xor(px, 16, 64));
      mx = fmaxf(mx, __shfl_xor(mx, 32, 64));
      mx = fmaxf(mx, m_);
      const float al = __builtin_amdgcn_exp2f(m_ - mx);
      m_ = mx;
      ls_ *= al;
      float aq[4];
#pragma unroll
      for (int r = 0; r < 4; r++) aq[r] = __shfl(al, lg * 4 + r, 64);
#pragma unroll
      for (int j = 0; j < 4; j++)
#pragma unroll
        for (int r = 0; r < 4; r++) o[j][r] *= aq[r];
    }

    float ps = 0.0f;
#pragma unroll
    for (int j = 0; j < 4; j++) {
      const float p0 = __builtin_amdgcn_exp2f(sfr[j][0] - m_);
      const float p1 = __builtin_amdgcn_exp2f(sfr[j][1] - m_);
      const float p2 = __builtin_amdgcn_exp2f(sfr[j][2] - m_);
      const float p3 = __builtin_amdgcn_exp2f(sfr[j][3] - m_);
      ps += (p0 + p1) + (p2 + p3);
      unsigned lo, hi;
      asm("v_cvt_pk_bf16_f32 %0, %1, %2" : "=v"(lo) : "v"(p0), "v"(p1));
      asm("v_cvt_pk_bf16_f32 %0, %1, %2" : "=v"(hi) : "v"(p2), "v"(p3));
      uint2 w; w.x = lo; w.y = hi;
      *(uint2*)(&Pl[wave][lr][j * 16 + lg * 4]) = w;
    }
    ls_ += ps;

    __builtin_amdgcn_s_setprio(1);
#pragma unroll
    for (int ks = 0; ks < 2; ks++) {
      bf16x8 pa = *(const bf16x8*)(&Pl[wave][lr][lg * 8 + ks * 32]);
#pragma unroll
      for (int j = 0; j < 4; j++) {
        bf16x8 vb = *(const bf16x8*)(&Vs[buf][(j * 16 + lr) * 64 + ((lg * 8 + ks * 32) ^ sw)]);
        o[j] = __builtin_amdgcn_mfma_f32_16x16x32_bf16(pa, vb, o[j], 0, 0, 0);
      }
    }
    __builtin_amdgcn_s_setprio(0);

    __syncthreads();
  }

  ls_ += __shfl_xor(ls_, 16, 64);
  ls_ += __shfl_xor(ls_, 32, 64);
  float lsq[4];
#pragma unroll
  for (int r = 0; r < 4; r++) lsq[r] = __shfl(ls_, lg * 4 + r, 64);

  const size_t orow = (size_t)(b * 1024 + qt * 128 + wave * 16 + lg * 4);
#pragma unroll
  for (int j = 0; j < 4; j++)
#pragma unroll
    for (int r = 0; r < 4; r++)
      out[(orow + r) * 512 + h * 64 + j * 16 + lr] = (bf16_t)(o[j][r] / lsq[r]);
}

// ------------------------------------------------------------------
// Step 0 top: s = state + pos + ts[0]; p = sigmoid(s . p_w + p_b);
// ACT halting update. Reads the input `state` directly (no copy).
// ------------------------------------------------------------------
__global__ __launch_bounds__(256)
void k_poshalt(const float* __restrict__ state, float* __restrict__ s,
               bf16_t* __restrict__ xbf,
               const float* __restrict__ pos, const float* __restrict__ ts,
               const float* __restrict__ pw, const float* __restrict__ pb,
               float* __restrict__ hp, float* __restrict__ rem, float* __restrict__ uw)
{
  const int row = blockIdx.x;
  const int l = row & 1023;
  const int t = threadIdx.x;
  const size_t base = (size_t)row * 512;
  float v0 = state[base + t]       + pos[l * 512 + t]       + ts[t];
  float v1 = state[base + 256 + t] + pos[l * 512 + 256 + t] + ts[256 + t];
  s[base + t] = v0; s[base + 256 + t] = v1;
  xbf[base + t] = (bf16_t)v0; xbf[base + 256 + t] = (bf16_t)v1;

  float d = v0 * pw[t] + v1 * pw[256 + t];
#pragma unroll
  for (int mk = 1; mk < 64; mk <<= 1) d += __shfl_xor(d, mk, 64);
  __shared__ float part[4];
  if ((t & 63) == 0) part[t >> 6] = d;
  __syncthreads();
  if (t == 0) {
    const float z = part[0] + part[1] + part[2] + part[3] + pb[0];
    const float p = 1.0f / (1.0f + expf(-z));
    float h = 0.0f, rm = 0.0f;
    const float cond = p;
    const float nh = (cond > 0.9f) ? 1.0f : 0.0f;
    const float st = (cond <= 0.9f) ? 1.0f : 0.0f;
    h += p * st;
    rm += nh * (1.0f - h);
    h += nh * rm;
    hp[row] = h; rem[row] = rm;
    uw[row] = p * st + nh * rm;
  }
}

// ------------------------------------------------------------------
// Post-attn LN: y = LayerNorm(s + oproj_bf16); write y bf16 only.
// ------------------------------------------------------------------
__global__ __launch_bounds__(256)
void k_addln1(const float* __restrict__ sIn, const bf16_t* __restrict__ ob,
              const float* __restrict__ g, const float* __restrict__ be,
              bf16_t* __restrict__ ybf, const int* __restrict__ bflag)
{
  if (bflag[blockIdx.x >> 10]) return;
  const int row = blockIdx.x, t = threadIdx.x;
  const size_t base = (size_t)row * 512 + 2 * t;
  f32x2 sv = *(const f32x2*)(sIn + base);
  bf16x2 ov = *(const bf16x2*)(ob + base);
  const float v0 = sv[0] + (float)ov[0];
  const float v1 = sv[1] + (float)ov[1];
  float s1 = v0 + v1, s2 = v0 * v0 + v1 * v1;
#pragma unroll
  for (int mk = 1; mk < 64; mk <<= 1) { s1 += __shfl_xor(s1, mk, 64); s2 += __shfl_xor(s2, mk, 64); }
  __shared__ float p1[4], p2[4];
  if ((t & 63) == 0) { p1[t >> 6] = s1; p2[t >> 6] = s2; }
  __syncthreads();
  s1 = p1[0] + p1[1] + p1[2] + p1[3];
  s2 = p2[0] + p2[1] + p2[2] + p2[3];
  const float mean = s1 * (1.0f / 512.0f);
  const float var  = s2 * (1.0f / 512.0f) - mean * mean;
  const float ri = rsqrtf(var + 1e-5f);
  f32x2 gv = *(const f32x2*)(g + 2 * t);
  f32x2 bv = *(const f32x2*)(be + 2 * t);
  bf16x2 yo;
  yo[0] = (bf16_t)((v0 - mean) * ri * gv[0] + bv[0]);
  yo[1] = (bf16_t)((v1 - mean) * ri * gv[1] + bv[1]);
  *(bf16x2*)(ybf + base) = yo;
}

// ------------------------------------------------------------------
// Fused bottom-of-step: y = LN(x1B + pA + pB) (bf16 inputs);
// prev = y*uw + prev*(1-uw); then NEXT step's pos/ts add + halting.
// ------------------------------------------------------------------
template <bool LAST>
__global__ __launch_bounds__(256)
void k_lnhalt(const bf16_t* __restrict__ x1b, const bf16_t* __restrict__ pA,
              const bf16_t* __restrict__ pB,
              const float* __restrict__ g, const float* __restrict__ be,
              const float* __restrict__ pos, const float* __restrict__ ts, int nstep,
              const float* __restrict__ pw, const float* __restrict__ pb,
              float* __restrict__ s, bf16_t* __restrict__ xbf,
              float* __restrict__ hp, float* __restrict__ rem, float* __restrict__ uw,
              float* __restrict__ prev, int step, const int* __restrict__ bflag)
{
  if (bflag[blockIdx.x >> 10]) return;
  const int row = blockIdx.x, t = threadIdx.x;
  const int l = row & 1023;
  const size_t base = (size_t)row * 512 + 2 * t;
  bf16x2 xv = *(const bf16x2*)(x1b + base);
  bf16x2 av = *(const bf16x2*)(pA + base);
  bf16x2 bv2 = *(const bf16x2*)(pB + base);
  const float a0 = (float)xv[0] + (float)av[0] + (float)bv2[0];
  const float a1 = (float)xv[1] + (float)av[1] + (float)bv2[1];
  float s1 = a0 + a1, s2 = a0 * a0 + a1 * a1;
#pragma unroll
  for (int mk = 1; mk < 64; mk <<= 1) { s1 += __shfl_xor(s1, mk, 64); s2 += __shfl_xor(s2, mk, 64); }
  __shared__ float p1[4], p2[4], pd[4];
  if ((t & 63) == 0) { p1[t >> 6] = s1; p2[t >> 6] = s2; }
  __syncthreads();
  s1 = p1[0] + p1[1] + p1[2] + p1[3];
  s2 = p2[0] + p2[1] + p2[2] + p2[3];
  const float mean = s1 * (1.0f / 512.0f);
  const float var  = s2 * (1.0f / 512.0f) - mean * mean;
  const float ri = rsqrtf(var + 1e-5f);
  f32x2 gv = *(const f32x2*)(g + 2 * t);
  f32x2 bev = *(const f32x2*)(be + 2 * t);
  const float y0 = (a0 - mean) * ri * gv[0] + bev[0];
  const float y1 = (a1 - mean) * ri * gv[1] + bev[1];

  const float w = uw[row];
  if (step == 0) {
    f32x2 np; np[0] = y0 * w; np[1] = y1 * w;
    *(f32x2*)(prev + base) = np;
  } else if (w != 0.0f) {
    f32x2 pv = *(const f32x2*)(prev + base);
    f32x2 np;
    np[0] = y0 * w + pv[0] * (1.0f - w);
    np[1] = y1 * w + pv[1] * (1.0f - w);
    *(f32x2*)(prev + base) = np;
  }

  if (LAST) return;

  f32x2 pp = *(const f32x2*)(pos + l * 512 + 2 * t);
  f32x2 tv = *(const f32x2*)(ts + nstep * 512 + 2 * t);
  const float v0 = y0 + pp[0] + tv[0];
  const float v1 = y1 + pp[1] + tv[1];
  f32x2 sv; sv[0] = v0; sv[1] = v1;
  *(f32x2*)(s + base) = sv;
  bf16x2 xo; xo[0] = (bf16_t)v0; xo[1] = (bf16_t)v1;
  *(bf16x2*)(xbf + base) = xo;

  f32x2 wv = *(const f32x2*)(pw + 2 * t);
  float d = v0 * wv[0] + v1 * wv[1];
#pragma unroll
  for (int mk = 1; mk < 64; mk <<= 1) d += __shfl_xor(d, mk, 64);
  if ((t & 63) == 0) pd[t >> 6] = d;
  __syncthreads();
  if (t == 0) {
    const float z = pd[0] + pd[1] + pd[2] + pd[3] + pb[0];
    const float p = 1.0f / (1.0f + expf(-z));
    float h  = hp[row];
    float rm = rem[row];
    const float still0 = (h < 1.0f) ? 1.0f : 0.0f;
    const float cond = h + p * still0;
    const float nh = (cond > 0.9f) ? still0 : 0.0f;
    const float st = (cond <= 0.9f) ? still0 : 0.0f;
    h += p * st;
    rm += nh * (1.0f - h);
    h += nh * rm;
    hp[row] = h; rem[row] = rm;
    uw[row] = p * st + nh * rm;
  }
}

// ------------------------------------------------------------------
// Per-batch dead detector: block b sets bflag[b]=1 once its 1024 rows
// all have hp >= 1 AND uw == 0. Monotone (never unset).
// ------------------------------------------------------------------
__global__ __launch_bounds__(256)
void k_flag(const float* __restrict__ hp, const float* __restrict__ uw,
            int* __restrict__ bflag)
{
  const int b = blockIdx.x;
  if (bflag[b]) return;
  const int t = threadIdx.x;
  const int base = b * 1024;
  float mn = 1e30f, mxw = 0.0f;
  {
    f32x4 v = *(const f32x4*)(hp + base + t * 4);
    f32x4 u = *(const f32x4*)(uw + base + t * 4);
#pragma unroll
    for (int q = 0; q < 4; q++) { mn = fminf(mn, v[q]); mxw = fmaxf(mxw, u[q]); }
  }
#pragma unroll
  for (int mk = 1; mk < 64; mk <<= 1) {
    mn = fminf(mn, __shfl_xor(mn, mk, 64));
    mxw = fmaxf(mxw, __shfl_xor(mxw, mk, 64));
  }
  __shared__ float part[4], partw[4];
  if ((t & 63) == 0) { part[t >> 6] = mn; partw[t >> 6] = mxw; }
  __syncthreads();
  if (t == 0) {
    mn = fminf(fminf(part[0], part[1]), fminf(part[2], part[3]));
    mxw = fmaxf(fmaxf(partw[0], partw[1]), fmaxf(partw[2], partw[3]));
    if (mn >= 1.0f && mxw == 0.0f) bflag[b] = 1;
  }
}

__global__ void k_zeroflag(int* __restrict__ bflag)
{
  if (threadIdx.x < 8) bflag[threadIdx.x] = 0;
}

// ------------------------------------------------------------------
__global__ void k_pos_ts(float* __restrict__ pos, float* __restrict__ ts,
                         const int* __restrict__ outer)
{
  const int idx = blockIdx.x * 256 + threadIdx.x;
  const int l = idx >> 9, i = idx & 511;
  const float dt = expf((float)(i & ~1) * (-9.210340371976184f / 512.0f));
  const float a = (float)l * dt;
  pos[idx] = (i & 1) ? cosf(a) : sinf(a);
  if (l < 6) {
    const int gidx = 6 * outer[0] + l;
    const float a2 = (float)gidx * dt;
    ts[l * 512 + i] = (i & 1) ? cosf(a2) : sinf(a2);
  }
}

__global__ void k_f2b(const float* __restrict__ in, bf16_t* __restrict__ out, int n)
{
  const int i = blockIdx.x * 256 + threadIdx.x;
  if (i < n) out[i] = (bf16_t)in[i];
}

__global__ void k_copy(const float* __restrict__ in, float* __restrict__ out, int n)
{
  const int i = blockIdx.x * 256 + threadIdx.x;
  if (i < n) out[i] = in[i];
}

// ------------------------------------------------------------------
extern "C" void kernel_launch(void* const* d_in, const int* in_sizes, int n_in,
                              void* d_out, int out_size, void* d_ws, size_t ws_size,
                              hipStream_t stream)
{
  const float* state = (const float*)d_in[0];
  const int*   outer = (const int*)d_in[1];
  const float* p_w   = (const float*)d_in[2];
  const float* p_b   = (const float*)d_in[3];
  const float* wq = (const float*)d_in[4];
  const float* bq = (const float*)d_in[5];
  const float* wk = (const float*)d_in[6];
  const float* bk = (const float*)d_in[7];
  const float* wv = (const float*)d_in[8];
  const float* bv = (const float*)d_in[9];
  const float* wo = (const float*)d_in[10];
  const float* bo = (const float*)d_in[11];
  const float* w1 = (const float*)d_in[12];
  const float* b1 = (const float*)d_in[13];
  const float* w2 = (const float*)d_in[14];
  const float* b2 = (const float*)d_in[15];
  const float* ln1g = (const float*)d_in[16];
  const float* ln1b = (const float*)d_in[17];
  const float* ln2g = (const float*)d_in[18];
  const float* ln2b = (const float*)d_in[19];
  float* prev = (float*)d_out;

  char* cur = (char*)d_ws;
  auto take = [&](size_t n) { char* p = cur; cur += (n + 255) & ~(size_t)255; return p; };
  float*  pos   = (float*) take((size_t)1024 * 512 * 4);
  float*  ts    = (float*) take(6 * 512 * 4);
  bf16_t* wqkvB = (bf16_t*)take((size_t)1536 * 512 * 2);
  bf16_t* woB   = (bf16_t*)take((size_t)512 * 512 * 2);
  bf16_t* w1B   = (bf16_t*)take((size_t)2048 * 512 * 2);
  bf16_t* w2B   = (bf16_t*)take((size_t)512 * 2048 * 2);
  float*  bqkv  = (float*) take(1536 * 4);
  float*  s     = (float*) take((size_t)8192 * 512 * 4);  // fp32 state
  bf16_t* x1B   = (bf16_t*)take((size_t)8192 * 512 * 2);  // LN1 output
  bf16_t* pA    = (bf16_t*)take((size_t)8192 * 512 * 2);  // FFN2 split-K half0
  char*   tmp   = take((size_t)8192 * 512 * 2);           // vt, then O-proj out
  bf16_t* attnO = (bf16_t*)take((size_t)8192 * 512 * 2);  // attn out, then FFN2 half1
  float*  hp    = (float*) take(8192 * 4);
  float*  rem   = (float*) take(8192 * 4);
  float*  uw    = (float*) take(8192 * 4);
  int*    bflag = (int*)   take(8 * 4);
  char*   region = take((size_t)8192 * 2048 * 2);
  bf16_t* xB  = (bf16_t*)region;
  bf16_t* qkv = (bf16_t*)(region + (size_t)8192 * 512 * 2);
  bf16_t* hB  = (bf16_t*)region;
  bf16_t* vt  = (bf16_t*)tmp;
  bf16_t* obf = (bf16_t*)tmp;
  bf16_t* pB  = attnO;

  // ---- precompute ----
  k_zeroflag<<<dim3(1), dim3(64), 0, stream>>>(bflag);
  k_pos_ts<<<dim3(2048), dim3(256), 0, stream>>>(pos, ts, outer);
  k_f2b<<<dim3(1024), dim3(256), 0, stream>>>(wq, wqkvB,               512 * 512);
  k_f2b<<<dim3(1024), dim3(256), 0, stream>>>(wk, wqkvB + 512 * 512,   512 * 512);
  k_f2b<<<dim3(1024), dim3(256), 0, stream>>>(wv, wqkvB + 1024 * 512,  512 * 512);
  k_f2b<<<dim3(1024), dim3(256), 0, stream>>>(wo, woB,                 512 * 512);
  k_f2b<<<dim3(4096), dim3(256), 0, stream>>>(w1, w1B,                 2048 * 512);
  k_f2b<<<dim3(4096), dim3(256), 0, stream>>>(w2, w2B,                 512 * 2048);
  k_copy<<<dim3(2), dim3(256), 0, stream>>>(bq, bqkv,        512);
  k_copy<<<dim3(2), dim3(256), 0, stream>>>(bk, bqkv + 512,  512);
  k_copy<<<dim3(2), dim3(256), 0, stream>>>(bv, bqkv + 1024, 512);

  // step 0 top: s = state + pos + ts[0]; halting gate (reads input directly)
  k_poshalt<<<dim3(8192), dim3(256), 0, stream>>>(state, s, xB, pos, ts, p_w, p_b, hp, rem, uw);

  // ---- 6 hops ----
  for (int step = 0; step < 6; step++) {
    gemm_bt<false, true ><<<dim3(64, 12), dim3(256), 0, stream>>>(xB, wqkvB, bqkv, qkv, vt, 8192, 1536, 512, bflag);
    k_attn<<<dim3(64, 8), dim3(512), 0, stream>>>(qkv, vt, attnO, bflag);
    gemm_bt512<<<dim3(64, 4, 1), dim3(512), 0, stream>>>(attnO, woB, bo, obf, nullptr, 8192, 512, 512, 512, bflag);
    k_addln1<<<dim3(8192), dim3(256), 0, stream>>>(s, obf, ln1g, ln1b, x1B, bflag);
    gemm_bt<true, false><<<dim3(64, 16), dim3(256), 0, stream>>>(x1B, w1B, b1, hB, nullptr, 8192, 2048, 512, bflag);
    gemm_bt512<<<dim3(64, 4, 2), dim3(512), 0, stream>>>(hB, w2B, b2, pA, pB, 8192, 512, 2048, 1024, bflag);
    if (step < 5) {
      k_lnhalt<false><<<dim3(8192), dim3(256), 0, stream>>>(x1B, pA, pB, ln2g, ln2b, pos, ts, step + 1,
                                                            p_w, p_b, s, xB, hp, rem, uw, prev, step, bflag);
      k_flag<<<dim3(8), dim3(256), 0, stream>>>(hp, uw, bflag);
    } else {
      k_lnhalt<true><<<dim3(8192), dim3(256), 0, stream>>>(x1B, pA, pB, ln2g, ln2b, pos, ts, 0,
                                                           p_w, p_b, s, xB, hp, rem, uw, prev, step, bflag);
    }
  }
}